// Round 1
// baseline (2280.578 us; speedup 1.0000x reference)
//
#include <hip/hip_runtime.h>
#include <math.h>

#define RR 32
#define R3 32768
#define BB 4
#define CI 64
#define CO 64
#define NN 4096

// ---------------- block reduce helpers ----------------
__device__ __forceinline__ float blockReduceSum(float v, float* sm) {
    int tid = threadIdx.x;
    sm[tid] = v; __syncthreads();
    for (int off = 128; off > 0; off >>= 1) {
        if (tid < off) sm[tid] += sm[tid + off];
        __syncthreads();
    }
    float r = sm[0]; __syncthreads();
    return r;
}
__device__ __forceinline__ float blockReduceMax(float v, float* sm) {
    int tid = threadIdx.x;
    sm[tid] = v; __syncthreads();
    for (int off = 128; off > 0; off >>= 1) {
        if (tid < off) sm[tid] = fmaxf(sm[tid], sm[tid + off]);
        __syncthreads();
    }
    float r = sm[0]; __syncthreads();
    return r;
}

// ---------------- voxel coords ----------------
__global__ void k_nc(const float* __restrict__ coords, float* __restrict__ nc,
                     int* __restrict__ vidx) {
    int b = blockIdx.x, tid = threadIdx.x;
    __shared__ float sm[256];
    const float* cb = coords + (size_t)b * 3 * NN;
    float s0 = 0, s1 = 0, s2 = 0;
    for (int n = tid; n < NN; n += 256) {
        s0 += cb[n]; s1 += cb[NN + n]; s2 += cb[2 * NN + n];
    }
    float m0 = blockReduceSum(s0, sm) * (1.0f / NN);
    float m1 = blockReduceSum(s1, sm) * (1.0f / NN);
    float m2 = blockReduceSum(s2, sm) * (1.0f / NN);
    float mx = 0;
    for (int n = tid; n < NN; n += 256) {
        float dx = cb[n] - m0, dy = cb[NN + n] - m1, dz = cb[2 * NN + n] - m2;
        mx = fmaxf(mx, dx * dx + dy * dy + dz * dz);
    }
    mx = blockReduceMax(mx, sm);
    float denom = 2.0f * sqrtf(mx);
    float mean[3] = {m0, m1, m2};
    for (int n = tid; n < NN; n += 256) {
        int vi[3];
        #pragma unroll
        for (int ax = 0; ax < 3; ax++) {
            float x = (cb[ax * NN + n] - mean[ax]) / denom + 0.5f;
            x = x * RR;
            x = fminf(fmaxf(x, 0.0f), (float)(RR - 1));
            nc[((size_t)b * 3 + ax) * NN + n] = x;
            vi[ax] = (int)rintf(x);
        }
        vidx[b * NN + n] = (vi[0] * RR + vi[1]) * RR + vi[2];
    }
}

// ---------------- scatter-mean ----------------
__global__ void k_scatter(const float* __restrict__ feat, const int* __restrict__ vidx,
                          float* __restrict__ grid, float* __restrict__ cnt) {
    int tid = threadIdx.x;
    int pid = blockIdx.x * 64 + (tid & 63);
    int cg = tid >> 6;
    int b = pid / NN, n = pid % NN;
    int idx = vidx[pid];
    if (cg == 0) atomicAdd(&cnt[b * R3 + idx], 1.0f);
    #pragma unroll 4
    for (int c = cg * 16; c < cg * 16 + 16; c++)
        atomicAdd(&grid[((size_t)(b * CI + c)) * R3 + idx], feat[((size_t)(b * CI + c)) * NN + n]);
}

__global__ void k_avg(float* __restrict__ grid, const float* __restrict__ cnt) {
    size_t i = (size_t)blockIdx.x * 256 + threadIdx.x;  // B*CI*R3
    int v = i & (R3 - 1);
    int b = i >> 21;  // /(CI*R3) = /2^21
    grid[i] = grid[i] / fmaxf(cnt[b * R3 + v], 1.0f);
}

// ---------------- conv3d 3x3x3, CI=CO=64 ----------------
// block: (tile 4x8x8 voxels, co-block of 16, b). threads 256.
// thread: 4 consecutive w voxels x 4 cos = 16 acc.
__global__ __launch_bounds__(256) void k_conv(const float* __restrict__ in,
                                              const float* __restrict__ w,
                                              const float* __restrict__ bias,
                                              float* __restrict__ out) {
    __shared__ float lin[4 * 600];      // 4 ci x 6*10*10 halo tile
    __shared__ float lw[4 * 27 * 16];   // [ci][k][co16]
    int tile = blockIdx.x;              // 128 tiles
    int cob = blockIdx.y;               // 4
    int b = blockIdx.z;
    int d0 = (tile >> 4) * 4, h0 = ((tile >> 2) & 3) * 8, w0 = (tile & 3) * 8;
    int tid = threadIdx.x;
    int vg = tid & 63, cog = tid >> 6;
    int dl = vg >> 4, hl = (vg >> 1) & 7, wl = (vg & 1) * 4;
    int co0 = cob * 16;
    float acc[4][4];
    #pragma unroll
    for (int a = 0; a < 4; a++)
        #pragma unroll
        for (int j = 0; j < 4; j++) acc[a][j] = 0.0f;

    for (int cc = 0; cc < 16; cc++) {
        int cbase = cc * 4;
        for (int i = tid; i < 2400; i += 256) {
            int ci = i / 600, r = i % 600;
            int dd = r / 100, hh = (r / 10) % 10, ww = r % 10;
            int gd = d0 - 1 + dd, gh = h0 - 1 + hh, gw = w0 - 1 + ww;
            float v = 0.0f;
            if ((unsigned)gd < RR && (unsigned)gh < RR && (unsigned)gw < RR)
                v = in[((size_t)(b * CI + cbase + ci)) * R3 + gd * 1024 + gh * 32 + gw];
            lin[i] = v;
        }
        for (int i = tid; i < 1728; i += 256) {
            int col = i & 15, k = (i >> 4) % 27, cil = i >> 4; cil /= 27;
            lw[i] = w[((size_t)(co0 + col) * CI + cbase + cil) * 27 + k];
        }
        __syncthreads();
        #pragma unroll
        for (int ci = 0; ci < 4; ci++) {
            #pragma unroll
            for (int kd = 0; kd < 3; kd++) {
                #pragma unroll
                for (int kh = 0; kh < 3; kh++) {
                    int base = ci * 600 + (dl + kd) * 100 + (hl + kh) * 10 + wl;
                    float pv[6];
                    #pragma unroll
                    for (int x = 0; x < 6; x++) pv[x] = lin[base + x];
                    #pragma unroll
                    for (int kw = 0; kw < 3; kw++) {
                        const float4 wv = *(const float4*)&lw[((ci * 27) + (kd * 9 + kh * 3 + kw)) * 16 + cog * 4];
                        float wa[4] = {wv.x, wv.y, wv.z, wv.w};
                        #pragma unroll
                        for (int cq = 0; cq < 4; cq++)
                            #pragma unroll
                            for (int j = 0; j < 4; j++)
                                acc[cq][j] += pv[kw + j] * wa[cq];
                    }
                }
            }
        }
        __syncthreads();
    }
    #pragma unroll
    for (int cq = 0; cq < 4; cq++) {
        int co = co0 + cog * 4 + cq;
        float bv = bias[co];
        float4 o;
        o.x = acc[cq][0] + bv; o.y = acc[cq][1] + bv;
        o.z = acc[cq][2] + bv; o.w = acc[cq][3] + bv;
        *(float4*)&out[((size_t)(b * CO + co)) * R3 + (d0 + dl) * 1024 + (h0 + hl) * 32 + (w0 + wl)] = o;
    }
}

// ---------------- BN3d stats (per channel over B*R3) ----------------
__global__ void k_bn_stats3d(const float* __restrict__ x, const float* __restrict__ g,
                             const float* __restrict__ be, float* __restrict__ stats) {
    int c = blockIdx.x, tid = threadIdx.x;
    __shared__ float rs[256], rq[256];
    float s = 0, sq = 0;
    for (int i = tid; i < BB * R3; i += 256) {
        int b = i >> 15, v = i & (R3 - 1);
        float val = x[((size_t)(b * CO + c)) * R3 + v];
        s += val; sq += val * val;
    }
    rs[tid] = s; rq[tid] = sq; __syncthreads();
    for (int off = 128; off > 0; off >>= 1) {
        if (tid < off) { rs[tid] += rs[tid + off]; rq[tid] += rq[tid + off]; }
        __syncthreads();
    }
    if (tid == 0) {
        float mean = rs[0] / (BB * R3);
        float var = rq[0] / (BB * R3) - mean * mean;
        float rstd = rsqrtf(var + 1e-4f);
        float scale = g[c] * rstd;
        stats[2 * c] = scale;
        stats[2 * c + 1] = be[c] - mean * scale;
    }
}

__global__ void k_bn_lrelu3d(float* __restrict__ x, const float* __restrict__ stats) {
    size_t i = (size_t)blockIdx.x * 256 + threadIdx.x;  // B*CO*R3
    int c = (i >> 15) & 63;
    float v = x[i] * stats[2 * c] + stats[2 * c + 1];
    x[i] = v > 0.0f ? v : 0.1f * v;
}

// ---------------- devoxelize (trilinear gather) ----------------
__global__ void k_devox(const float* __restrict__ v2, const float* __restrict__ nc,
                        float* __restrict__ out) {
    int b = blockIdx.y;
    int n = blockIdx.x * 64 + (threadIdx.x & 63);
    int cg = threadIdx.x >> 6;
    float x = nc[((size_t)b * 3 + 0) * NN + n];
    float y = nc[((size_t)b * 3 + 1) * NN + n];
    float z = nc[((size_t)b * 3 + 2) * NN + n];
    float fx = floorf(x), fy = floorf(y), fz = floorf(z);
    int lx = (int)fx, ly = (int)fy, lz = (int)fz;
    int hx = min(lx + 1, RR - 1), hy = min(ly + 1, RR - 1), hz = min(lz + 1, RR - 1);
    float frx = x - fx, fry = y - fy, frz = z - fz;
    int xx[2] = {lx, hx}, yy[2] = {ly, hy}, zz[2] = {lz, hz};
    float wx[2] = {1.0f - frx, frx}, wy[2] = {1.0f - fry, fry}, wz[2] = {1.0f - frz, frz};
    int idx[8]; float wt[8];
    #pragma unroll
    for (int dx = 0; dx < 2; dx++)
        #pragma unroll
        for (int dy = 0; dy < 2; dy++)
            #pragma unroll
            for (int dz = 0; dz < 2; dz++) {
                idx[dx * 4 + dy * 2 + dz] = (xx[dx] * RR + yy[dy]) * RR + zz[dz];
                wt[dx * 4 + dy * 2 + dz] = wx[dx] * wy[dy] * wz[dz];
            }
    for (int c = cg * 16; c < cg * 16 + 16; c++) {
        const float* g = v2 + ((size_t)(b * CO + c)) * R3;
        float s = 0;
        #pragma unroll
        for (int k = 0; k < 8; k++) s += g[idx[k]] * wt[k];
        out[((size_t)(b * CO + c)) * NN + n] = s;
    }
}

// ---------------- fuzzy attention: fz_feat = softmax(10*cn.cn^T) @ feat^T ----------------
__global__ __launch_bounds__(256) void k_fuzzy(const float* __restrict__ coords,
                                               const float* __restrict__ feat,
                                               float* __restrict__ fzf) {
    __shared__ float cm[3][64];
    __shared__ float fm[64][72];  // [m][c], padded stride 72
    int b = blockIdx.y;
    int n0 = blockIdx.x * 64;
    int tid = threadIdx.x, nl = tid & 63, cg = tid >> 6;
    int n = n0 + nl;
    float c0 = coords[((size_t)b * 3 + 0) * NN + n];
    float c1 = coords[((size_t)b * 3 + 1) * NN + n];
    float c2 = coords[((size_t)b * 3 + 2) * NN + n];
    float nr = sqrtf(c0 * c0 + c1 * c1 + c2 * c2);
    float iv = 1.0f / fmaxf(nr, 1e-12f);
    c0 *= iv; c1 *= iv; c2 *= iv;
    float acc[16];
    #pragma unroll
    for (int j = 0; j < 16; j++) acc[j] = 0.0f;
    float den = 0.0f;
    for (int m0 = 0; m0 < NN; m0 += 64) {
        __syncthreads();
        for (int i = tid; i < 4096; i += 256) {
            int c = i >> 6, m = i & 63;
            fm[m][c] = feat[((size_t)(b * CI + c)) * NN + m0 + m];
        }
        if (tid < 64) {
            int m = tid;
            float a0 = coords[((size_t)b * 3 + 0) * NN + m0 + m];
            float a1 = coords[((size_t)b * 3 + 1) * NN + m0 + m];
            float a2 = coords[((size_t)b * 3 + 2) * NN + m0 + m];
            float r = sqrtf(a0 * a0 + a1 * a1 + a2 * a2);
            float ivm = 1.0f / fmaxf(r, 1e-12f);
            cm[0][m] = a0 * ivm; cm[1][m] = a1 * ivm; cm[2][m] = a2 * ivm;
        }
        __syncthreads();
        #pragma unroll 4
        for (int mm = 0; mm < 64; mm++) {
            float s = c0 * cm[0][mm] + c1 * cm[1][mm] + c2 * cm[2][mm];
            float e = __expf(s * 10.0f);
            den += e;
            const float4* fp = (const float4*)&fm[mm][cg * 16];
            float4 f0 = fp[0], f1 = fp[1], f2 = fp[2], f3 = fp[3];
            acc[0] += e * f0.x; acc[1] += e * f0.y; acc[2] += e * f0.z; acc[3] += e * f0.w;
            acc[4] += e * f1.x; acc[5] += e * f1.y; acc[6] += e * f1.z; acc[7] += e * f1.w;
            acc[8] += e * f2.x; acc[9] += e * f2.y; acc[10] += e * f2.z; acc[11] += e * f2.w;
            acc[12] += e * f3.x; acc[13] += e * f3.y; acc[14] += e * f3.z; acc[15] += e * f3.w;
        }
    }
    float id = 1.0f / den;
    #pragma unroll
    for (int j = 0; j < 16; j++)
        fzf[((size_t)(b * CI + cg * 16 + j)) * NN + n] = acc[j] * id;
}

// ---------------- 1x1 conv: out[b,o,n] = sum_c W[o,c]*in[b,c,n] + bias[o] ----------------
template <int NSEG>
__global__ void k_1x1(const float* __restrict__ inA, const float* __restrict__ inB,
                      const float* __restrict__ inC, const float* __restrict__ w,
                      const float* __restrict__ bias, float* __restrict__ out) {
    __shared__ float lw[NSEG * 64 * 16];
    int b = blockIdx.z, ob = blockIdx.y;
    int n = blockIdx.x * 256 + threadIdx.x;
    int tid = threadIdx.x;
    const int CI3 = NSEG * 64;
    for (int i = tid; i < CI3 * 16; i += 256) {
        int o = i & 15, c = i >> 4;
        lw[i] = w[(size_t)(ob * 16 + o) * CI3 + c];
    }
    __syncthreads();
    float acc[16];
    #pragma unroll
    for (int j = 0; j < 16; j++) acc[j] = 0.0f;
    const float* segs[3] = {inA, inB, inC};
    #pragma unroll
    for (int sseg = 0; sseg < NSEG; sseg++) {
        const float* src = segs[sseg] + (size_t)(b * 64) * NN + n;
        for (int c = 0; c < 64; c++) {
            float x = src[(size_t)c * NN];
            const float* wrow = &lw[(sseg * 64 + c) * 16];
            #pragma unroll
            for (int j = 0; j < 16; j++) acc[j] += x * wrow[j];
        }
    }
    #pragma unroll
    for (int j = 0; j < 16; j++)
        out[((size_t)(b * 64 + ob * 16 + j)) * NN + n] = acc[j] + bias[ob * 16 + j];
}

// ---------------- BN1d stats (per channel over B*N) ----------------
__global__ void k_bn_stats1d(const float* __restrict__ x, const float* __restrict__ g,
                             const float* __restrict__ be, float* __restrict__ stats) {
    int c = blockIdx.x, tid = threadIdx.x;
    __shared__ float rs[256], rq[256];
    float s = 0, sq = 0;
    for (int i = tid; i < BB * NN; i += 256) {
        int b = i >> 12, n = i & (NN - 1);
        float val = x[((size_t)(b * 64 + c)) * NN + n];
        s += val; sq += val * val;
    }
    rs[tid] = s; rq[tid] = sq; __syncthreads();
    for (int off = 128; off > 0; off >>= 1) {
        if (tid < off) { rs[tid] += rs[tid + off]; rq[tid] += rq[tid + off]; }
        __syncthreads();
    }
    if (tid == 0) {
        float mean = rs[0] / (BB * NN);
        float var = rq[0] / (BB * NN) - mean * mean;
        float rstd = rsqrtf(var + 1e-4f);
        float scale = g[c] * rstd;
        stats[2 * c] = scale;
        stats[2 * c + 1] = be[c] - mean * scale;
    }
}

__global__ void k_bn_relu1d(const float* __restrict__ x, const float* __restrict__ stats,
                            float* __restrict__ out) {
    size_t i = (size_t)blockIdx.x * 256 + threadIdx.x;  // B*64*N
    int c = (i >> 12) & 63;
    float v = x[i] * stats[2 * c] + stats[2 * c + 1];
    out[i] = v > 0.0f ? v : 0.0f;
}

// ---------------- launcher ----------------
extern "C" void kernel_launch(void* const* d_in, const int* in_sizes, int n_in,
                              void* d_out, int out_size, void* d_ws, size_t ws_size,
                              hipStream_t stream) {
    const float* features = (const float*)d_in[0];
    const float* coords = (const float*)d_in[1];
    const float* w1 = (const float*)d_in[2];
    const float* b1 = (const float*)d_in[3];
    const float* g1 = (const float*)d_in[4];
    const float* be1 = (const float*)d_in[5];
    const float* w2 = (const float*)d_in[6];
    const float* b2 = (const float*)d_in[7];
    const float* g2 = (const float*)d_in[8];
    const float* be2 = (const float*)d_in[9];
    const float* wp = (const float*)d_in[10];
    const float* bp = (const float*)d_in[11];
    const float* gp = (const float*)d_in[12];
    const float* bep = (const float*)d_in[13];
    const float* wf = (const float*)d_in[14];
    const float* bf = (const float*)d_in[15];
    const float* wfu = (const float*)d_in[16];
    const float* bfu = (const float*)d_in[17];
    const float* gfu = (const float*)d_in[18];
    const float* befu = (const float*)d_in[19];

    float* ws = (float*)d_ws;
    float* nc = ws;                       // 49152
    int* vidx = (int*)(ws + 49152);       // 16384
    float* cnt = ws + 65536;              // 131072
    float* gridA = ws + 196608;           // 8388608
    float* gridB = ws + 8585216;          // 8388608
    float* stats = ws + 16973824;         // 512
    float* vox = ws + 16974336;           // 1048576
    float* pt = vox + 1048576;
    float* fzf = pt + 1048576;
    float* fzc = fzf + 1048576;
    float* fpre = fzc + 1048576;

    float* out = (float*)d_out;

    // zero cnt + gridA (contiguous)
    hipMemsetAsync(cnt, 0, (size_t)(131072 + 8388608) * 4, stream);

    k_nc<<<BB, 256, 0, stream>>>(coords, nc, vidx);
    k_scatter<<<BB * NN / 64, 256, 0, stream>>>(features, vidx, gridA, cnt);
    k_avg<<<BB * CI * R3 / 256, 256, 0, stream>>>(gridA, cnt);

    k_conv<<<dim3(128, 4, BB), 256, 0, stream>>>(gridA, w1, b1, gridB);
    k_bn_stats3d<<<64, 256, 0, stream>>>(gridB, g1, be1, stats);
    k_bn_lrelu3d<<<BB * CO * R3 / 256, 256, 0, stream>>>(gridB, stats);

    k_conv<<<dim3(128, 4, BB), 256, 0, stream>>>(gridB, w2, b2, gridA);
    k_bn_stats3d<<<64, 256, 0, stream>>>(gridA, g2, be2, stats + 128);
    k_bn_lrelu3d<<<BB * CO * R3 / 256, 256, 0, stream>>>(gridA, stats + 128);

    k_devox<<<dim3(NN / 64, BB), 256, 0, stream>>>(gridA, nc, vox);

    k_fuzzy<<<dim3(NN / 64, BB), 256, 0, stream>>>(coords, features, fzf);

    k_1x1<1><<<dim3(NN / 256, 4, BB), 256, 0, stream>>>(features, nullptr, nullptr, wp, bp, pt);
    k_bn_stats1d<<<64, 256, 0, stream>>>(pt, gp, bep, stats + 256);
    k_bn_relu1d<<<BB * 64 * NN / 256, 256, 0, stream>>>(pt, stats + 256, pt);

    k_1x1<1><<<dim3(NN / 256, 4, BB), 256, 0, stream>>>(fzf, nullptr, nullptr, wf, bf, fzc);

    k_1x1<3><<<dim3(NN / 256, 4, BB), 256, 0, stream>>>(vox, pt, fzc, wfu, bfu, fpre);
    k_bn_stats1d<<<64, 256, 0, stream>>>(fpre, gfu, befu, stats + 384);
    k_bn_relu1d<<<BB * 64 * NN / 256, 256, 0, stream>>>(fpre, stats + 384, out);

    hipMemcpyAsync(out + (size_t)BB * CO * NN, coords, (size_t)BB * 3 * NN * 4,
                   hipMemcpyDeviceToDevice, stream);
}

// Round 2
// 1174.879 us; speedup vs baseline: 1.9411x; 1.9411x over previous
//
#include <hip/hip_runtime.h>
#include <math.h>

#define RR 32
#define R3 32768
#define BB 4
#define CI 64
#define CO 64
#define NN 4096

// ---------------- block reduce helpers ----------------
__device__ __forceinline__ float blockReduceSum(float v, float* sm) {
    int tid = threadIdx.x;
    sm[tid] = v; __syncthreads();
    for (int off = 128; off > 0; off >>= 1) {
        if (tid < off) sm[tid] += sm[tid + off];
        __syncthreads();
    }
    float r = sm[0]; __syncthreads();
    return r;
}
__device__ __forceinline__ float blockReduceMax(float v, float* sm) {
    int tid = threadIdx.x;
    sm[tid] = v; __syncthreads();
    for (int off = 128; off > 0; off >>= 1) {
        if (tid < off) sm[tid] = fmaxf(sm[tid], sm[tid + off]);
        __syncthreads();
    }
    float r = sm[0]; __syncthreads();
    return r;
}

// ---------------- voxel coords ----------------
__global__ void k_nc(const float* __restrict__ coords, float* __restrict__ nc,
                     int* __restrict__ vidx) {
    int b = blockIdx.x, tid = threadIdx.x;
    __shared__ float sm[256];
    const float* cb = coords + (size_t)b * 3 * NN;
    float s0 = 0, s1 = 0, s2 = 0;
    for (int n = tid; n < NN; n += 256) {
        s0 += cb[n]; s1 += cb[NN + n]; s2 += cb[2 * NN + n];
    }
    float m0 = blockReduceSum(s0, sm) * (1.0f / NN);
    float m1 = blockReduceSum(s1, sm) * (1.0f / NN);
    float m2 = blockReduceSum(s2, sm) * (1.0f / NN);
    float mx = 0;
    for (int n = tid; n < NN; n += 256) {
        float dx = cb[n] - m0, dy = cb[NN + n] - m1, dz = cb[2 * NN + n] - m2;
        mx = fmaxf(mx, dx * dx + dy * dy + dz * dz);
    }
    mx = blockReduceMax(mx, sm);
    float denom = 2.0f * sqrtf(mx);
    float mean[3] = {m0, m1, m2};
    for (int n = tid; n < NN; n += 256) {
        int vi[3];
        #pragma unroll
        for (int ax = 0; ax < 3; ax++) {
            float x = (cb[ax * NN + n] - mean[ax]) / denom + 0.5f;
            x = x * RR;
            x = fminf(fmaxf(x, 0.0f), (float)(RR - 1));
            nc[((size_t)b * 3 + ax) * NN + n] = x;
            vi[ax] = (int)rintf(x);
        }
        vidx[b * NN + n] = (vi[0] * RR + vi[1]) * RR + vi[2];
    }
}

// ---------------- scatter-mean ----------------
__global__ void k_scatter(const float* __restrict__ feat, const int* __restrict__ vidx,
                          float* __restrict__ grid, float* __restrict__ cnt) {
    int tid = threadIdx.x;
    int pid = blockIdx.x * 64 + (tid & 63);
    int cg = tid >> 6;
    int b = pid / NN, n = pid % NN;
    int idx = vidx[pid];
    if (cg == 0) atomicAdd(&cnt[b * R3 + idx], 1.0f);
    #pragma unroll 4
    for (int c = cg * 16; c < cg * 16 + 16; c++)
        atomicAdd(&grid[((size_t)(b * CI + c)) * R3 + idx], feat[((size_t)(b * CI + c)) * NN + n]);
}

__global__ void k_avg(float* __restrict__ grid, const float* __restrict__ cnt) {
    size_t i4 = (size_t)blockIdx.x * 256 + threadIdx.x;  // f4 index over B*CI*R3/4
    int v0 = (int)((i4 << 2) & (R3 - 1));
    int b = (int)(i4 >> 19);
    float4 g = ((float4*)grid)[i4];
    const float4 ct = *(const float4*)&cnt[b * R3 + v0];
    g.x /= fmaxf(ct.x, 1.0f); g.y /= fmaxf(ct.y, 1.0f);
    g.z /= fmaxf(ct.z, 1.0f); g.w /= fmaxf(ct.w, 1.0f);
    ((float4*)grid)[i4] = g;
}

// ---------------- transposes ----------------
__global__ void k_tfeat(const float* __restrict__ feat, float* __restrict__ featT) {
    __shared__ float t[64][65];
    int b = blockIdx.y, n0 = blockIdx.x * 64, tid = threadIdx.x;
    int q = tid >> 6, nl = tid & 63;
    #pragma unroll
    for (int k = 0; k < 16; k++) {
        int c = q * 16 + k;
        t[nl][c] = feat[((size_t)(b * CI + c)) * NN + n0 + nl];
    }
    __syncthreads();
    #pragma unroll
    for (int k = 0; k < 16; k++) {
        int n = q * 16 + k;
        featT[((size_t)b * NN + n0 + n) * 64 + nl] = t[n][nl];
    }
}

// wT[(ci*27 + k)*64 + co] = w[(co*CI + ci)*27 + k]
__global__ void k_twt(const float* __restrict__ w, float* __restrict__ wT) {
    int i = blockIdx.x * 256 + threadIdx.x;  // 110592
    int co = i & 63, r = i >> 6;
    int k = r % 27, ci = r / 27;
    wT[i] = w[((size_t)co * CI + ci) * 27 + k];
}

// ---------------- conv3d 3x3x3 v3 ----------------
// grid (128 tiles, 2 cob, B), 256 thr. Wave = one co-slice of 8 (uniform -> s_load weights).
// thread: 8 co x 4 w outputs. LDS holds only the input tile (rows padded to 12).
__global__ __launch_bounds__(256) void k_conv(const float* __restrict__ in,
                                              const float* __restrict__ wT,
                                              const float* __restrict__ bias,
                                              float* __restrict__ out) {
    __shared__ float lin[2880];  // 4 ci x 6d x 10h x 12w(pad)
    int tile = blockIdx.x, cob = blockIdx.y, b = blockIdx.z;
    int d0 = (tile >> 4) * 4, h0 = ((tile >> 2) & 3) * 8, w0 = (tile & 3) * 8;
    int tid = threadIdx.x;
    int cog = __builtin_amdgcn_readfirstlane(tid >> 6);
    int s = tid & 63;
    int dl = s >> 4, hl = (s >> 1) & 7, wl = (s & 1) * 4;
    int co = cob * 32 + cog * 8;
    float acc[8][4];
    #pragma unroll
    for (int j = 0; j < 8; j++)
        #pragma unroll
        for (int x = 0; x < 4; x++) acc[j][x] = 0.0f;

    for (int cc = 0; cc < 16; cc++) {
        int cbase = cc * 4;
        __syncthreads();
        for (int i = tid; i < 2400; i += 256) {
            int ci = i / 600, r = i % 600;
            int dd = r / 100, r2 = r % 100;
            int hh = r2 / 10, ww = r2 % 10;
            int gd = d0 - 1 + dd, gh = h0 - 1 + hh, gw = w0 - 1 + ww;
            float v = 0.0f;
            if ((unsigned)gd < RR && (unsigned)gh < RR && (unsigned)gw < RR)
                v = in[((size_t)(b * CI + cbase + ci)) * R3 + gd * 1024 + gh * 32 + gw];
            lin[ci * 720 + (dd * 10 + hh) * 12 + ww] = v;
        }
        __syncthreads();
        #pragma unroll
        for (int ci = 0; ci < 4; ci++) {
            const float* wci = wT + ((size_t)(cbase + ci) * 27) * 64 + co;
            #pragma unroll
            for (int kd = 0; kd < 3; kd++) {
                #pragma unroll
                for (int kh = 0; kh < 3; kh++) {
                    int rr = (dl + kd) * 10 + (hl + kh);
                    int base = ci * 720 + rr * 12 + wl;
                    float4 pa = *(const float4*)&lin[base];
                    float2 pb = *(const float2*)&lin[base + 4];
                    float pv[6] = {pa.x, pa.y, pa.z, pa.w, pb.x, pb.y};
                    #pragma unroll
                    for (int kw = 0; kw < 3; kw++) {
                        const float* wk = wci + (kd * 9 + kh * 3 + kw) * 64;
                        float4 wv0 = *(const float4*)wk;
                        float4 wv1 = *(const float4*)(wk + 4);
                        float wa[8] = {wv0.x, wv0.y, wv0.z, wv0.w, wv1.x, wv1.y, wv1.z, wv1.w};
                        #pragma unroll
                        for (int j = 0; j < 8; j++)
                            #pragma unroll
                            for (int x = 0; x < 4; x++)
                                acc[j][x] += pv[kw + x] * wa[j];
                    }
                }
            }
        }
    }
    #pragma unroll
    for (int j = 0; j < 8; j++) {
        float bv = bias[co + j];
        float4 o;
        o.x = acc[j][0] + bv; o.y = acc[j][1] + bv;
        o.z = acc[j][2] + bv; o.w = acc[j][3] + bv;
        *(float4*)&out[((size_t)(b * CO + co + j)) * R3 + (d0 + dl) * 1024 + (h0 + hl) * 32 + w0 + wl] = o;
    }
}

// ---------------- BN stats (2-stage) ----------------
__global__ void k_bnstat_a(const float* __restrict__ x, float* __restrict__ pst, int len) {
    int c = blockIdx.x, b = blockIdx.y, tid = threadIdx.x;
    const float4* xp = (const float4*)(x + ((size_t)(b * 64 + c)) * len);
    int n4 = len >> 2;
    float s = 0, q = 0;
    for (int i = tid; i < n4; i += 256) {
        float4 v = xp[i];
        s += v.x + v.y + v.z + v.w;
        q += v.x * v.x + v.y * v.y + v.z * v.z + v.w * v.w;
    }
    __shared__ float rs[256], rq[256];
    rs[tid] = s; rq[tid] = q; __syncthreads();
    for (int off = 128; off > 0; off >>= 1) {
        if (tid < off) { rs[tid] += rs[tid + off]; rq[tid] += rq[tid + off]; }
        __syncthreads();
    }
    if (tid == 0) {
        pst[(c * gridDim.y + b) * 2] = rs[0];
        pst[(c * gridDim.y + b) * 2 + 1] = rq[0];
    }
}

__global__ void k_bnfin(const float* __restrict__ pst, const float* __restrict__ g,
                        const float* __restrict__ be, float* __restrict__ stats,
                        int nb, float invcnt) {
    int c = threadIdx.x;
    float s = 0, q = 0;
    for (int b = 0; b < nb; b++) {
        s += pst[(c * nb + b) * 2];
        q += pst[(c * nb + b) * 2 + 1];
    }
    float mean = s * invcnt;
    float var = q * invcnt - mean * mean;
    float sc = g[c] * rsqrtf(var + 1e-4f);
    stats[2 * c] = sc;
    stats[2 * c + 1] = be[c] - mean * sc;
}

// apply: y = act(x*scale+shift), f4-wide. shift_log2 = log2(f4 elems per (b,c))
__global__ void k_bn_act(const float* __restrict__ x, const float* __restrict__ stats,
                         float* __restrict__ out, int shift, float slope) {
    size_t i = (size_t)blockIdx.x * 256 + threadIdx.x;
    int c = (int)((i >> shift) & 63);
    float sc = stats[2 * c], sh = stats[2 * c + 1];
    float4 v = ((const float4*)x)[i];
    v.x = v.x * sc + sh; v.y = v.y * sc + sh; v.z = v.z * sc + sh; v.w = v.w * sc + sh;
    v.x = v.x > 0 ? v.x : slope * v.x;
    v.y = v.y > 0 ? v.y : slope * v.y;
    v.z = v.z > 0 ? v.z : slope * v.z;
    v.w = v.w > 0 ? v.w : slope * v.w;
    ((float4*)out)[i] = v;
}

// ---------------- devoxelize ----------------
__global__ void k_devox(const float* __restrict__ v2, const float* __restrict__ nc,
                        float* __restrict__ out) {
    int b = blockIdx.y;
    int n = blockIdx.x * 64 + (threadIdx.x & 63);
    int cg = threadIdx.x >> 6;
    float x = nc[((size_t)b * 3 + 0) * NN + n];
    float y = nc[((size_t)b * 3 + 1) * NN + n];
    float z = nc[((size_t)b * 3 + 2) * NN + n];
    float fx = floorf(x), fy = floorf(y), fz = floorf(z);
    int lx = (int)fx, ly = (int)fy, lz = (int)fz;
    int hx = min(lx + 1, RR - 1), hy = min(ly + 1, RR - 1), hz = min(lz + 1, RR - 1);
    float frx = x - fx, fry = y - fy, frz = z - fz;
    int xx[2] = {lx, hx}, yy[2] = {ly, hy}, zz[2] = {lz, hz};
    float wx[2] = {1.0f - frx, frx}, wy[2] = {1.0f - fry, fry}, wz[2] = {1.0f - frz, frz};
    int idx[8]; float wt[8];
    #pragma unroll
    for (int dx = 0; dx < 2; dx++)
        #pragma unroll
        for (int dy = 0; dy < 2; dy++)
            #pragma unroll
            for (int dz = 0; dz < 2; dz++) {
                idx[dx * 4 + dy * 2 + dz] = (xx[dx] * RR + yy[dy]) * RR + zz[dz];
                wt[dx * 4 + dy * 2 + dz] = wx[dx] * wy[dy] * wz[dz];
            }
    for (int c = cg * 16; c < cg * 16 + 16; c++) {
        const float* g = v2 + ((size_t)(b * CO + c)) * R3;
        float s = 0;
        #pragma unroll
        for (int k = 0; k < 8; k++) s += g[idx[k]] * wt[k];
        out[((size_t)(b * CO + c)) * NN + n] = s;
    }
}

// ---------------- fuzzy attention v2 ----------------
// grid (16 n-tiles, 8 m-chunks, B), 256 thr, 4 n/thread, 16 ch/thread.
__global__ __launch_bounds__(256, 2) void k_fuzzy(const float* __restrict__ coords,
                                                  const float* __restrict__ featT,
                                                  float* __restrict__ pnum,
                                                  float* __restrict__ pden) {
    __shared__ float fm[64][72];
    __shared__ float cm[3][512];
    int b = blockIdx.z, mc = blockIdx.y, nt = blockIdx.x;
    int tid = threadIdx.x, cg = tid >> 6, lane = tid & 63;
    int n0 = nt * 256, m0 = mc * 512;

    #pragma unroll
    for (int r = 0; r < 2; r++) {
        int m = r * 256 + tid;
        float a0 = coords[((size_t)b * 3 + 0) * NN + m0 + m];
        float a1 = coords[((size_t)b * 3 + 1) * NN + m0 + m];
        float a2 = coords[((size_t)b * 3 + 2) * NN + m0 + m];
        float inv = 1.0f / fmaxf(sqrtf(a0 * a0 + a1 * a1 + a2 * a2), 1e-12f);
        cm[0][m] = a0 * inv; cm[1][m] = a1 * inv; cm[2][m] = a2 * inv;
    }

    float cn0[4], cn1[4], cn2[4];
    #pragma unroll
    for (int j = 0; j < 4; j++) {
        int n = n0 + lane + 64 * j;
        float a0 = coords[((size_t)b * 3 + 0) * NN + n];
        float a1 = coords[((size_t)b * 3 + 1) * NN + n];
        float a2 = coords[((size_t)b * 3 + 2) * NN + n];
        float inv = 10.0f / fmaxf(sqrtf(a0 * a0 + a1 * a1 + a2 * a2), 1e-12f);
        cn0[j] = a0 * inv; cn1[j] = a1 * inv; cn2[j] = a2 * inv;
    }

    float acc[4][16];
    #pragma unroll
    for (int j = 0; j < 4; j++)
        #pragma unroll
        for (int q = 0; q < 16; q++) acc[j][q] = 0.0f;
    float den[4] = {0, 0, 0, 0};

    for (int ms = 0; ms < 8; ms++) {
        __syncthreads();
        #pragma unroll
        for (int r = 0; r < 4; r++) {
            int i = r * 256 + tid;
            int mr = i >> 4, c4 = i & 15;
            *(float4*)&fm[mr][c4 * 4] =
                *(const float4*)&featT[((size_t)b * NN + m0 + ms * 64 + mr) * 64 + c4 * 4];
        }
        __syncthreads();
        for (int mm = 0; mm < 64; mm++) {
            int m = ms * 64 + mm;
            float b0 = cm[0][m], b1 = cm[1][m], b2 = cm[2][m];
            const float4* fp = (const float4*)&fm[mm][cg * 16];
            float4 f0 = fp[0], f1 = fp[1], f2 = fp[2], f3 = fp[3];
            #pragma unroll
            for (int j = 0; j < 4; j++) {
                float sdot = cn0[j] * b0 + cn1[j] * b1 + cn2[j] * b2;
                float e = __expf(sdot);
                den[j] += e;
                acc[j][0] += e * f0.x; acc[j][1] += e * f0.y;
                acc[j][2] += e * f0.z; acc[j][3] += e * f0.w;
                acc[j][4] += e * f1.x; acc[j][5] += e * f1.y;
                acc[j][6] += e * f1.z; acc[j][7] += e * f1.w;
                acc[j][8] += e * f2.x; acc[j][9] += e * f2.y;
                acc[j][10] += e * f2.z; acc[j][11] += e * f2.w;
                acc[j][12] += e * f3.x; acc[j][13] += e * f3.y;
                acc[j][14] += e * f3.z; acc[j][15] += e * f3.w;
            }
        }
    }
    #pragma unroll
    for (int j = 0; j < 4; j++) {
        int n = n0 + lane + 64 * j;
        #pragma unroll
        for (int q = 0; q < 16; q++)
            pnum[(((size_t)(b * 8 + mc) * 64) + cg * 16 + q) * NN + n] = acc[j][q];
        if (cg == 0) pden[((size_t)(b * 8 + mc)) * NN + n] = den[j];
    }
}

__global__ void k_combine(const float* __restrict__ pnum, const float* __restrict__ pden,
                          float* __restrict__ fzf) {
    int i = blockIdx.x * 256 + threadIdx.x;  // B*64*NN
    int b = i >> 18, c = (i >> 12) & 63, n = i & 4095;
    float num = 0, den = 0;
    #pragma unroll
    for (int ch = 0; ch < 8; ch++) {
        num += pnum[(((size_t)(b * 8 + ch) * 64) + c) * NN + n];
        den += pden[((size_t)(b * 8 + ch)) * NN + n];
    }
    fzf[((size_t)(b * 64 + c)) * NN + n] = num / den;
}

// ---------------- 1x1 conv ----------------
template <int NSEG>
__global__ __launch_bounds__(256) void k_1x1(const float* __restrict__ inA,
                                             const float* __restrict__ inB,
                                             const float* __restrict__ inC,
                                             const float* __restrict__ w,
                                             const float* __restrict__ bias,
                                             float* __restrict__ out) {
    __shared__ float lw[NSEG * 64 * 16];
    int b = blockIdx.z, ob = blockIdx.y;
    int n = blockIdx.x * 64 + (threadIdx.x & 63);
    int og = threadIdx.x >> 6;
    const int CI3 = NSEG * 64;
    for (int i = threadIdx.x; i < CI3 * 16; i += 256) {
        int c = i >> 4, o = i & 15;
        lw[c * 16 + o] = w[(size_t)(ob * 16 + o) * CI3 + c];
    }
    __syncthreads();
    float acc[4] = {0, 0, 0, 0};
    const float* segs[3] = {inA, inB, inC};
    #pragma unroll
    for (int sg = 0; sg < NSEG; sg++) {
        const float* src = segs[sg] + (size_t)b * 64 * NN + n;
        #pragma unroll 8
        for (int c = 0; c < 64; c++) {
            float x = src[(size_t)c * NN];
            float4 wv = *(const float4*)&lw[(sg * 64 + c) * 16 + og * 4];
            acc[0] += x * wv.x; acc[1] += x * wv.y;
            acc[2] += x * wv.z; acc[3] += x * wv.w;
        }
    }
    #pragma unroll
    for (int j = 0; j < 4; j++)
        out[((size_t)(b * 64 + ob * 16 + og * 4 + j)) * NN + n] = acc[j] + bias[ob * 16 + og * 4 + j];
}

// ---------------- launcher ----------------
extern "C" void kernel_launch(void* const* d_in, const int* in_sizes, int n_in,
                              void* d_out, int out_size, void* d_ws, size_t ws_size,
                              hipStream_t stream) {
    const float* features = (const float*)d_in[0];
    const float* coords = (const float*)d_in[1];
    const float* w1 = (const float*)d_in[2];
    const float* b1 = (const float*)d_in[3];
    const float* g1 = (const float*)d_in[4];
    const float* be1 = (const float*)d_in[5];
    const float* w2 = (const float*)d_in[6];
    const float* b2 = (const float*)d_in[7];
    const float* g2 = (const float*)d_in[8];
    const float* be2 = (const float*)d_in[9];
    const float* wp = (const float*)d_in[10];
    const float* bp = (const float*)d_in[11];
    const float* gp = (const float*)d_in[12];
    const float* bep = (const float*)d_in[13];
    const float* wf = (const float*)d_in[14];
    const float* bf = (const float*)d_in[15];
    const float* wfu = (const float*)d_in[16];
    const float* bfu = (const float*)d_in[17];
    const float* gfu = (const float*)d_in[18];
    const float* befu = (const float*)d_in[19];

    float* ws = (float*)d_ws;
    float* nc = ws;                        // 49152
    int* vidx = (int*)(ws + 49152);        // 16384 ints (reused as pstats later)
    float* pst = ws + 49152;               // overlay on vidx (used after scatter)
    float* cnt = ws + 65536;               // 131072 (reused as pden)
    float* pden = cnt;
    float* gridA = ws + 196608;            // 8388608
    float* gridB = ws + 8585216;           // 8388608 (reused as pnum before conv1)
    float* pnum = gridB;
    float* stats = ws + 16973824;          // 512
    float* vox = ws + 16974336;            // 1048576 (wT1/wT2 live here until devox)
    float* wT1 = vox;
    float* wT2 = vox + 110592;
    float* pt = vox + 1048576;             // 1048576
    float* fzf = pt + 1048576;
    float* fzc = fzf + 1048576;
    float* fpre = fzc + 1048576;           // 1048576 (featT overlays, consumed early)
    float* featT = fpre;

    float* out = (float*)d_out;

    hipMemsetAsync(cnt, 0, (size_t)(131072 + 8388608) * 4, stream);

    // prep
    k_tfeat<<<dim3(64, BB), 256, 0, stream>>>(features, featT);
    k_twt<<<432, 256, 0, stream>>>(w1, wT1);
    k_twt<<<432, 256, 0, stream>>>(w2, wT2);
    k_nc<<<BB, 256, 0, stream>>>(coords, nc, vidx);
    k_scatter<<<BB * NN / 64, 256, 0, stream>>>(features, vidx, gridA, cnt);
    k_avg<<<BB * CI * R3 / 4 / 256, 256, 0, stream>>>(gridA, cnt);

    // fuzzy branch (uses gridB as pnum scratch; must finish before conv1)
    k_fuzzy<<<dim3(16, 8, BB), 256, 0, stream>>>(coords, featT, pnum, pden);
    k_combine<<<BB * 64 * NN / 256, 256, 0, stream>>>(pnum, pden, fzf);

    // voxel branch
    k_conv<<<dim3(128, 2, BB), 256, 0, stream>>>(gridA, wT1, b1, gridB);
    k_bnstat_a<<<dim3(64, BB), 256, 0, stream>>>(gridB, pst, R3);
    k_bnfin<<<1, 64, 0, stream>>>(pst, g1, be1, stats, BB, 1.0f / (BB * R3));
    k_bn_act<<<BB * CO * R3 / 4 / 256, 256, 0, stream>>>(gridB, stats, gridB, 13, 0.1f);

    k_conv<<<dim3(128, 2, BB), 256, 0, stream>>>(gridB, wT2, b2, gridA);
    k_bnstat_a<<<dim3(64, BB), 256, 0, stream>>>(gridA, pst, R3);
    k_bnfin<<<1, 64, 0, stream>>>(pst, g2, be2, stats + 128, BB, 1.0f / (BB * R3));
    k_bn_act<<<BB * CO * R3 / 4 / 256, 256, 0, stream>>>(gridA, stats + 128, gridA, 13, 0.1f);

    k_devox<<<dim3(NN / 64, BB), 256, 0, stream>>>(gridA, nc, vox);

    // point branch
    k_1x1<1><<<dim3(NN / 64, 4, BB), 256, 0, stream>>>(features, nullptr, nullptr, wp, bp, pt);
    k_bnstat_a<<<dim3(64, BB), 256, 0, stream>>>(pt, pst, NN);
    k_bnfin<<<1, 64, 0, stream>>>(pst, gp, bep, stats + 256, BB, 1.0f / (BB * NN));
    k_bn_act<<<BB * 64 * NN / 4 / 256, 256, 0, stream>>>(pt, stats + 256, pt, 10, 0.0f);

    // fuzzy proj
    k_1x1<1><<<dim3(NN / 64, 4, BB), 256, 0, stream>>>(fzf, nullptr, nullptr, wf, bf, fzc);

    // fusion
    k_1x1<3><<<dim3(NN / 64, 4, BB), 256, 0, stream>>>(vox, pt, fzc, wfu, bfu, fpre);
    k_bnstat_a<<<dim3(64, BB), 256, 0, stream>>>(fpre, pst, NN);
    k_bnfin<<<1, 64, 0, stream>>>(pst, gfu, befu, stats + 384, BB, 1.0f / (BB * NN));
    k_bn_act<<<BB * 64 * NN / 4 / 256, 256, 0, stream>>>(fpre, stats + 384, out, 10, 0.0f);

    hipMemcpyAsync(out + (size_t)BB * CO * NN, coords, (size_t)BB * 3 * NN * 4,
                   hipMemcpyDeviceToDevice, stream);
}

// Round 3
// 601.647 us; speedup vs baseline: 3.7906x; 1.9528x over previous
//
#include <hip/hip_runtime.h>
#include <math.h>

#define RR 32
#define R3 32768
#define BB 4
#define CI 64
#define CO 64
#define NN 4096

typedef short v8s __attribute__((ext_vector_type(8)));
typedef float v4f __attribute__((ext_vector_type(4)));
typedef unsigned short ushort_t;

__device__ __forceinline__ unsigned short f2bf(float f) {
    unsigned int u = __float_as_uint(f);
    unsigned int r = (u + 0x7FFFu + ((u >> 16) & 1u)) >> 16;
    return (unsigned short)r;
}

// ---------------- block reduce helpers ----------------
__device__ __forceinline__ float blockReduceSum(float v, float* sm) {
    int tid = threadIdx.x;
    sm[tid] = v; __syncthreads();
    for (int off = 128; off > 0; off >>= 1) {
        if (tid < off) sm[tid] += sm[tid + off];
        __syncthreads();
    }
    float r = sm[0]; __syncthreads();
    return r;
}
__device__ __forceinline__ float blockReduceMax(float v, float* sm) {
    int tid = threadIdx.x;
    sm[tid] = v; __syncthreads();
    for (int off = 128; off > 0; off >>= 1) {
        if (tid < off) sm[tid] = fmaxf(sm[tid], sm[tid + off]);
        __syncthreads();
    }
    float r = sm[0]; __syncthreads();
    return r;
}

// ---------------- voxel coords ----------------
__global__ void k_nc(const float* __restrict__ coords, float* __restrict__ nc,
                     int* __restrict__ vidx) {
    int b = blockIdx.x, tid = threadIdx.x;
    __shared__ float sm[256];
    const float* cb = coords + (size_t)b * 3 * NN;
    float s0 = 0, s1 = 0, s2 = 0;
    for (int n = tid; n < NN; n += 256) {
        s0 += cb[n]; s1 += cb[NN + n]; s2 += cb[2 * NN + n];
    }
    float m0 = blockReduceSum(s0, sm) * (1.0f / NN);
    float m1 = blockReduceSum(s1, sm) * (1.0f / NN);
    float m2 = blockReduceSum(s2, sm) * (1.0f / NN);
    float mx = 0;
    for (int n = tid; n < NN; n += 256) {
        float dx = cb[n] - m0, dy = cb[NN + n] - m1, dz = cb[2 * NN + n] - m2;
        mx = fmaxf(mx, dx * dx + dy * dy + dz * dz);
    }
    mx = blockReduceMax(mx, sm);
    float denom = 2.0f * sqrtf(mx);
    float mean[3] = {m0, m1, m2};
    for (int n = tid; n < NN; n += 256) {
        int vi[3];
        #pragma unroll
        for (int ax = 0; ax < 3; ax++) {
            float x = (cb[ax * NN + n] - mean[ax]) / denom + 0.5f;
            x = x * RR;
            x = fminf(fmaxf(x, 0.0f), (float)(RR - 1));
            nc[((size_t)b * 3 + ax) * NN + n] = x;
            vi[ax] = (int)rintf(x);
        }
        vidx[b * NN + n] = (vi[0] * RR + vi[1]) * RR + vi[2];
    }
}

// ---------------- scatter-mean ----------------
__global__ void k_scatter(const float* __restrict__ feat, const int* __restrict__ vidx,
                          float* __restrict__ grid, float* __restrict__ cnt) {
    int tid = threadIdx.x;
    int pid = blockIdx.x * 64 + (tid & 63);
    int cg = tid >> 6;
    int b = pid / NN, n = pid % NN;
    int idx = vidx[pid];
    if (cg == 0) atomicAdd(&cnt[b * R3 + idx], 1.0f);
    #pragma unroll 4
    for (int c = cg * 16; c < cg * 16 + 16; c++)
        atomicAdd(&grid[((size_t)(b * CI + c)) * R3 + idx], feat[((size_t)(b * CI + c)) * NN + n]);
}

__global__ void k_avg(float* __restrict__ grid, const float* __restrict__ cnt) {
    size_t i4 = (size_t)blockIdx.x * 256 + threadIdx.x;  // f4 index over B*CI*R3/4
    int v0 = (int)((i4 << 2) & (R3 - 1));
    int b = (int)(i4 >> 19);
    float4 g = ((float4*)grid)[i4];
    const float4 ct = *(const float4*)&cnt[b * R3 + v0];
    g.x /= fmaxf(ct.x, 1.0f); g.y /= fmaxf(ct.y, 1.0f);
    g.z /= fmaxf(ct.z, 1.0f); g.w /= fmaxf(ct.w, 1.0f);
    ((float4*)grid)[i4] = g;
}

// ---------------- feature transpose (for fuzzy) ----------------
__global__ void k_tfeat(const float* __restrict__ feat, float* __restrict__ featT) {
    __shared__ float t[64][65];
    int b = blockIdx.y, n0 = blockIdx.x * 64, tid = threadIdx.x;
    int q = tid >> 6, nl = tid & 63;
    #pragma unroll
    for (int k = 0; k < 16; k++) {
        int c = q * 16 + k;
        t[nl][c] = feat[((size_t)(b * CI + c)) * NN + n0 + nl];
    }
    __syncthreads();
    #pragma unroll
    for (int k = 0; k < 16; k++) {
        int n = q * 16 + k;
        featT[((size_t)b * NN + n0 + n) * 64 + nl] = t[n][nl];
    }
}

// ---------------- weight transform: wB[k][co][ci] bf16 ----------------
__global__ void k_twb(const float* __restrict__ w, ushort_t* __restrict__ wB) {
    int i = blockIdx.x * 256 + threadIdx.x;  // 27*64*64 = 110592
    int ci = i & 63, t = i >> 6;
    int co = t & 63, k = t >> 6;
    wB[i] = f2bf(w[((size_t)co * CI + ci) * 27 + k]);
}

// ---------------- fused (optional BN+lrelu) + transpose + bf16 cast ----------------
// in: x f32 [b][64][R3]; out: o bf16 [b][R3][64]
__global__ void k_t2bf(const float* __restrict__ x, const float* __restrict__ stats,
                       float slope, ushort_t* __restrict__ o) {
    __shared__ float ld[64][65];
    int b = blockIdx.y, s0 = blockIdx.x * 64, tid = threadIdx.x;
    int sl = tid & 63, cq = tid >> 6;
    const float* xb = x + (size_t)b * 64 * R3;
    #pragma unroll
    for (int k = 0; k < 16; k++) {
        int c = cq * 16 + k;
        ld[sl][c] = xb[(size_t)c * R3 + s0 + sl];
    }
    __syncthreads();
    int v = tid >> 2, q = tid & 3;
    unsigned int pk[8];
    #pragma unroll
    for (int j = 0; j < 8; j++) {
        int c = q * 16 + j * 2;
        float a = ld[v][c], d = ld[v][c + 1];
        if (stats) {
            a = a * stats[2 * c] + stats[2 * c + 1];
            d = d * stats[2 * c + 2] + stats[2 * c + 3];
            a = a > 0 ? a : slope * a;
            d = d > 0 ? d : slope * d;
        }
        pk[j] = (unsigned int)f2bf(a) | ((unsigned int)f2bf(d) << 16);
    }
    uint4* op = (uint4*)(o + ((size_t)(b * R3 + s0 + v)) * 64 + q * 16);
    op[0] = make_uint4(pk[0], pk[1], pk[2], pk[3]);
    op[1] = make_uint4(pk[4], pk[5], pk[6], pk[7]);
}

// ---------------- MFMA conv3d 3x3x3 ----------------
// gT: bf16 [b][z][y][x][ci]; wB: bf16 [k27][co][ci]; out: f32 [b][co][R3]
// block: 256 thr = 4 waves; covers z0 (1), y-octet (8), x (32) = 256 voxels, all 64 co.
// wave w: y = yt*8 + w*2 + {0,1}. n-frags f: (dy=f>>1, xh=f&1). m-frags: co 16-blocks.
// K-steps: 27 offsets x 2 ci-halves, reg-double-buffered direct global loads.
#define LOADKS(ks, AR, BR)                                                        \
  do {                                                                            \
    int _k = (ks) >> 1, _cih = (ks) & 1;                                          \
    int _dz = _k / 9, _rr = _k % 9, _dy = _rr / 3, _dx = _rr % 3;                 \
    unsigned _offin = (unsigned)((_dz * 1024 + _dy * 32 + _dx) * 64 + _cih * 32); \
    unsigned _offw = (unsigned)(_k * 4096 + _cih * 32);                           \
    _Pragma("unroll") for (int _f = 0; _f < 4; _f++)                              \
        BR[_f] = *(const v8s*)(sb[_f] + (lo[_f] + _offin));                       \
    _Pragma("unroll") for (int _m = 0; _m < 4; _m++)                              \
        AR[_m] = *(const v8s*)(wB + (loA[_m] + _offw));                           \
  } while (0)

#define MFMAKS(ks, AR, BR)                                                        \
  do {                                                                            \
    int _k = (ks) >> 1;                                                           \
    int _dz = _k / 9, _rr = _k % 9, _dy = _rr / 3, _dx = _rr % 3;                 \
    bool _zok = (unsigned)(z0 + _dz - 1) < 32u;                                   \
    v8s _bm[4];                                                                   \
    _Pragma("unroll") for (int _f = 0; _f < 4; _f++) {                            \
      bool _yok = (unsigned)(yw0 + (_f >> 1) + _dy - 1) < 32u;                    \
      bool _xok = (unsigned)((_f & 1) * 16 + l15 + _dx - 1) < 32u;                \
      _bm[_f] = (_zok && _yok && _xok) ? BR[_f] : vzero;                          \
    }                                                                             \
    _Pragma("unroll") for (int _m = 0; _m < 4; _m++)                              \
      _Pragma("unroll") for (int _f = 0; _f < 4; _f++)                            \
        acc[_m][_f] = __builtin_amdgcn_mfma_f32_16x16x32_bf16(AR[_m], _bm[_f],    \
                                                              acc[_m][_f], 0, 0, 0); \
  } while (0)

__global__ __launch_bounds__(256) void k_convm(const ushort_t* __restrict__ gT,
                                               const ushort_t* __restrict__ wB,
                                               float* __restrict__ out) {
    int z0 = blockIdx.x, yt = blockIdx.y, b = blockIdx.z;
    int tid = threadIdx.x;
    int w = __builtin_amdgcn_readfirstlane(tid >> 6);
    int lane = tid & 63;
    int l15 = lane & 15, l4 = lane >> 4;
    int yw0 = yt * 8 + w * 2;

    const ushort_t* gTb = gT + (size_t)b * R3 * 64;
    const ushort_t* sb[4];
    unsigned lo[4], loA[4];
    #pragma unroll
    for (int f = 0; f < 4; f++) {
        sb[f] = gTb + ((z0 - 1) * 1024 + (yw0 + (f >> 1) - 1) * 32 - 1) * 64;
        lo[f] = (unsigned)((((f & 1) * 16 + l15) * 64) + l4 * 8);
    }
    #pragma unroll
    for (int m = 0; m < 4; m++)
        loA[m] = (unsigned)(((m * 16 + l15) * 64) + l4 * 8);

    const v8s vzero = {};
    v4f acc[4][4];
    #pragma unroll
    for (int m = 0; m < 4; m++)
        #pragma unroll
        for (int f = 0; f < 4; f++)
            acc[m][f] = (v4f){0.0f, 0.0f, 0.0f, 0.0f};

    v8s A0[4], B0[4], A1[4], B1[4];
    LOADKS(0, A0, B0);
    for (int t = 0; t < 54; t += 2) {
        LOADKS(t + 1, A1, B1);
        MFMAKS(t, A0, B0);
        if (t < 52) LOADKS(t + 2, A0, B0);
        MFMAKS(t + 1, A1, B1);
    }

    // D: col(lane&15)=voxel-x within frag, row((lane>>4)*4+r)=co within m-frag
    #pragma unroll
    for (int m = 0; m < 4; m++) {
        #pragma unroll
        for (int f = 0; f < 4; f++) {
            int y = yw0 + (f >> 1);
            int x = (f & 1) * 16 + l15;
            #pragma unroll
            for (int r = 0; r < 4; r++) {
                int co = m * 16 + l4 * 4 + r;
                out[((size_t)(b * CO + co)) * R3 + z0 * 1024 + y * 32 + x] = acc[m][f][r];
            }
        }
    }
}

// ---------------- BN stats (2-stage) ----------------
__global__ void k_bnstat_a(const float* __restrict__ x, float* __restrict__ pst, int len) {
    int c = blockIdx.x, b = blockIdx.y, tid = threadIdx.x;
    const float4* xp = (const float4*)(x + ((size_t)(b * 64 + c)) * len);
    int n4 = len >> 2;
    float s = 0, q = 0;
    for (int i = tid; i < n4; i += 256) {
        float4 v = xp[i];
        s += v.x + v.y + v.z + v.w;
        q += v.x * v.x + v.y * v.y + v.z * v.z + v.w * v.w;
    }
    __shared__ float rs[256], rq[256];
    rs[tid] = s; rq[tid] = q; __syncthreads();
    for (int off = 128; off > 0; off >>= 1) {
        if (tid < off) { rs[tid] += rs[tid + off]; rq[tid] += rq[tid + off]; }
        __syncthreads();
    }
    if (tid == 0) {
        pst[(c * gridDim.y + b) * 2] = rs[0];
        pst[(c * gridDim.y + b) * 2 + 1] = rq[0];
    }
}

__global__ void k_bnfin(const float* __restrict__ pst, const float* __restrict__ g,
                        const float* __restrict__ be, float* __restrict__ stats,
                        int nb, float invcnt) {
    int c = threadIdx.x;
    float s = 0, q = 0;
    for (int b = 0; b < nb; b++) {
        s += pst[(c * nb + b) * 2];
        q += pst[(c * nb + b) * 2 + 1];
    }
    float mean = s * invcnt;
    float var = q * invcnt - mean * mean;
    float sc = g[c] * rsqrtf(var + 1e-4f);
    stats[2 * c] = sc;
    stats[2 * c + 1] = be[c] - mean * sc;
}

__global__ void k_bn_act(const float* __restrict__ x, const float* __restrict__ stats,
                         float* __restrict__ out, int shift, float slope) {
    size_t i = (size_t)blockIdx.x * 256 + threadIdx.x;
    int c = (int)((i >> shift) & 63);
    float sc = stats[2 * c], sh = stats[2 * c + 1];
    float4 v = ((const float4*)x)[i];
    v.x = v.x * sc + sh; v.y = v.y * sc + sh; v.z = v.z * sc + sh; v.w = v.w * sc + sh;
    v.x = v.x > 0 ? v.x : slope * v.x;
    v.y = v.y > 0 ? v.y : slope * v.y;
    v.z = v.z > 0 ? v.z : slope * v.z;
    v.w = v.w > 0 ? v.w : slope * v.w;
    ((float4*)out)[i] = v;
}

// ---------------- devoxelize ----------------
__global__ void k_devox(const float* __restrict__ v2, const float* __restrict__ nc,
                        float* __restrict__ out) {
    int b = blockIdx.y;
    int n = blockIdx.x * 64 + (threadIdx.x & 63);
    int cg = threadIdx.x >> 6;
    float x = nc[((size_t)b * 3 + 0) * NN + n];
    float y = nc[((size_t)b * 3 + 1) * NN + n];
    float z = nc[((size_t)b * 3 + 2) * NN + n];
    float fx = floorf(x), fy = floorf(y), fz = floorf(z);
    int lx = (int)fx, ly = (int)fy, lz = (int)fz;
    int hx = min(lx + 1, RR - 1), hy = min(ly + 1, RR - 1), hz = min(lz + 1, RR - 1);
    float frx = x - fx, fry = y - fy, frz = z - fz;
    int xx[2] = {lx, hx}, yy[2] = {ly, hy}, zz[2] = {lz, hz};
    float wx[2] = {1.0f - frx, frx}, wy[2] = {1.0f - fry, fry}, wz[2] = {1.0f - frz, frz};
    int idx[8]; float wt[8];
    #pragma unroll
    for (int dx = 0; dx < 2; dx++)
        #pragma unroll
        for (int dy = 0; dy < 2; dy++)
            #pragma unroll
            for (int dz = 0; dz < 2; dz++) {
                idx[dx * 4 + dy * 2 + dz] = (xx[dx] * RR + yy[dy]) * RR + zz[dz];
                wt[dx * 4 + dy * 2 + dz] = wx[dx] * wy[dy] * wz[dz];
            }
    for (int c = cg * 16; c < cg * 16 + 16; c++) {
        const float* g = v2 + ((size_t)(b * CO + c)) * R3;
        float s = 0;
        #pragma unroll
        for (int k = 0; k < 8; k++) s += g[idx[k]] * wt[k];
        out[((size_t)(b * CO + c)) * NN + n] = s;
    }
}

// ---------------- fuzzy attention ----------------
__global__ __launch_bounds__(256, 2) void k_fuzzy(const float* __restrict__ coords,
                                                  const float* __restrict__ featT,
                                                  float* __restrict__ pnum,
                                                  float* __restrict__ pden) {
    __shared__ float fm[64][72];
    __shared__ float cm[3][512];
    int b = blockIdx.z, mc = blockIdx.y, nt = blockIdx.x;
    int tid = threadIdx.x, cg = tid >> 6, lane = tid & 63;
    int n0 = nt * 256, m0 = mc * 512;

    #pragma unroll
    for (int r = 0; r < 2; r++) {
        int m = r * 256 + tid;
        float a0 = coords[((size_t)b * 3 + 0) * NN + m0 + m];
        float a1 = coords[((size_t)b * 3 + 1) * NN + m0 + m];
        float a2 = coords[((size_t)b * 3 + 2) * NN + m0 + m];
        float inv = 1.0f / fmaxf(sqrtf(a0 * a0 + a1 * a1 + a2 * a2), 1e-12f);
        cm[0][m] = a0 * inv; cm[1][m] = a1 * inv; cm[2][m] = a2 * inv;
    }

    float cn0[4], cn1[4], cn2[4];
    #pragma unroll
    for (int j = 0; j < 4; j++) {
        int n = n0 + lane + 64 * j;
        float a0 = coords[((size_t)b * 3 + 0) * NN + n];
        float a1 = coords[((size_t)b * 3 + 1) * NN + n];
        float a2 = coords[((size_t)b * 3 + 2) * NN + n];
        float inv = 10.0f / fmaxf(sqrtf(a0 * a0 + a1 * a1 + a2 * a2), 1e-12f);
        cn0[j] = a0 * inv; cn1[j] = a1 * inv; cn2[j] = a2 * inv;
    }

    float acc[4][16];
    #pragma unroll
    for (int j = 0; j < 4; j++)
        #pragma unroll
        for (int q = 0; q < 16; q++) acc[j][q] = 0.0f;
    float den[4] = {0, 0, 0, 0};

    for (int ms = 0; ms < 8; ms++) {
        __syncthreads();
        #pragma unroll
        for (int r = 0; r < 4; r++) {
            int i = r * 256 + tid;
            int mr = i >> 4, c4 = i & 15;
            *(float4*)&fm[mr][c4 * 4] =
                *(const float4*)&featT[((size_t)b * NN + m0 + ms * 64 + mr) * 64 + c4 * 4];
        }
        __syncthreads();
        for (int mm = 0; mm < 64; mm++) {
            int m = ms * 64 + mm;
            float b0 = cm[0][m], b1 = cm[1][m], b2 = cm[2][m];
            const float4* fp = (const float4*)&fm[mm][cg * 16];
            float4 f0 = fp[0], f1 = fp[1], f2 = fp[2], f3 = fp[3];
            #pragma unroll
            for (int j = 0; j < 4; j++) {
                float sdot = cn0[j] * b0 + cn1[j] * b1 + cn2[j] * b2;
                float e = __expf(sdot);
                den[j] += e;
                acc[j][0] += e * f0.x; acc[j][1] += e * f0.y;
                acc[j][2] += e * f0.z; acc[j][3] += e * f0.w;
                acc[j][4] += e * f1.x; acc[j][5] += e * f1.y;
                acc[j][6] += e * f1.z; acc[j][7] += e * f1.w;
                acc[j][8] += e * f2.x; acc[j][9] += e * f2.y;
                acc[j][10] += e * f2.z; acc[j][11] += e * f2.w;
                acc[j][12] += e * f3.x; acc[j][13] += e * f3.y;
                acc[j][14] += e * f3.z; acc[j][15] += e * f3.w;
            }
        }
    }
    #pragma unroll
    for (int j = 0; j < 4; j++) {
        int n = n0 + lane + 64 * j;
        #pragma unroll
        for (int q = 0; q < 16; q++)
            pnum[(((size_t)(b * 8 + mc) * 64) + cg * 16 + q) * NN + n] = acc[j][q];
        if (cg == 0) pden[((size_t)(b * 8 + mc)) * NN + n] = den[j];
    }
}

__global__ void k_combine(const float* __restrict__ pnum, const float* __restrict__ pden,
                          float* __restrict__ fzf) {
    int i = blockIdx.x * 256 + threadIdx.x;  // B*64*NN
    int b = i >> 18, c = (i >> 12) & 63, n = i & 4095;
    float num = 0, den = 0;
    #pragma unroll
    for (int ch = 0; ch < 8; ch++) {
        num += pnum[(((size_t)(b * 8 + ch) * 64) + c) * NN + n];
        den += pden[((size_t)(b * 8 + ch)) * NN + n];
    }
    fzf[((size_t)(b * 64 + c)) * NN + n] = num / den;
}

// ---------------- 1x1 conv ----------------
template <int NSEG>
__global__ __launch_bounds__(256) void k_1x1(const float* __restrict__ inA,
                                             const float* __restrict__ inB,
                                             const float* __restrict__ inC,
                                             const float* __restrict__ w,
                                             const float* __restrict__ bias,
                                             float* __restrict__ out) {
    __shared__ float lw[NSEG * 64 * 16];
    int b = blockIdx.z, ob = blockIdx.y;
    int n = blockIdx.x * 64 + (threadIdx.x & 63);
    int og = threadIdx.x >> 6;
    const int CI3 = NSEG * 64;
    for (int i = threadIdx.x; i < CI3 * 16; i += 256) {
        int c = i >> 4, o = i & 15;
        lw[c * 16 + o] = w[(size_t)(ob * 16 + o) * CI3 + c];
    }
    __syncthreads();
    float acc[4] = {0, 0, 0, 0};
    const float* segs[3] = {inA, inB, inC};
    #pragma unroll
    for (int sg = 0; sg < NSEG; sg++) {
        const float* src = segs[sg] + (size_t)b * 64 * NN + n;
        #pragma unroll 8
        for (int c = 0; c < 64; c++) {
            float x = src[(size_t)c * NN];
            float4 wv = *(const float4*)&lw[(sg * 64 + c) * 16 + og * 4];
            acc[0] += x * wv.x; acc[1] += x * wv.y;
            acc[2] += x * wv.z; acc[3] += x * wv.w;
        }
    }
    #pragma unroll
    for (int j = 0; j < 4; j++)
        out[((size_t)(b * 64 + ob * 16 + og * 4 + j)) * NN + n] = acc[j] + bias[ob * 16 + og * 4 + j];
}

// ---------------- launcher ----------------
extern "C" void kernel_launch(void* const* d_in, const int* in_sizes, int n_in,
                              void* d_out, int out_size, void* d_ws, size_t ws_size,
                              hipStream_t stream) {
    const float* features = (const float*)d_in[0];
    const float* coords = (const float*)d_in[1];
    const float* w1 = (const float*)d_in[2];
    // b1 (d_in[3]) skipped: cancelled exactly by BN1 mean subtraction
    const float* g1 = (const float*)d_in[4];
    const float* be1 = (const float*)d_in[5];
    const float* w2 = (const float*)d_in[6];
    // b2 (d_in[7]) skipped: cancelled by BN2
    const float* g2 = (const float*)d_in[8];
    const float* be2 = (const float*)d_in[9];
    const float* wp = (const float*)d_in[10];
    const float* bp = (const float*)d_in[11];
    const float* gp = (const float*)d_in[12];
    const float* bep = (const float*)d_in[13];
    const float* wf = (const float*)d_in[14];
    const float* bf = (const float*)d_in[15];
    const float* wfu = (const float*)d_in[16];
    const float* bfu = (const float*)d_in[17];
    const float* gfu = (const float*)d_in[18];
    const float* befu = (const float*)d_in[19];

    float* ws = (float*)d_ws;
    float* nc = ws;                        // 49152
    int* vidx = (int*)(ws + 49152);        // 16384 (pst overlays after scatter)
    float* pst = ws + 49152;
    float* cnt = ws + 65536;               // 131072 (pden overlays after k_avg)
    float* pden = cnt;
    float* gridA = ws + 196608;            // 8388608 f32 work grid
    float* gTpool = ws + 8585216;          // 8388608 floats: gT bf16 (first 4.2M floats) / pnum later
    ushort_t* gT = (ushort_t*)gTpool;
    float* pnum = gTpool;
    float* stats = ws + 16973824;          // 512
    float* voxreg = ws + 16974336;         // 1048576 (wB1/wB2 live here until devox)
    ushort_t* wB1 = (ushort_t*)voxreg;     // 110592 ushorts
    ushort_t* wB2 = wB1 + 110592;
    float* vox = voxreg;
    float* pt = ws + 18022912;
    float* fzf = ws + 19071488;
    float* fzc = ws + 20120064;
    float* fpre = ws + 21168640;           // featT overlays (consumed by fuzzy)
    float* featT = fpre;

    float* out = (float*)d_out;

    hipMemsetAsync(cnt, 0, (size_t)(131072 + 8388608) * 4, stream);

    // prep
    k_tfeat<<<dim3(64, BB), 256, 0, stream>>>(features, featT);
    k_twb<<<432, 256, 0, stream>>>(w1, wB1);
    k_twb<<<432, 256, 0, stream>>>(w2, wB2);
    k_nc<<<BB, 256, 0, stream>>>(coords, nc, vidx);
    k_scatter<<<BB * NN / 64, 256, 0, stream>>>(features, vidx, gridA, cnt);
    k_avg<<<BB * CI * R3 / 4 / 256, 256, 0, stream>>>(gridA, cnt);

    // voxel branch (MFMA convs)
    k_t2bf<<<dim3(512, BB), 256, 0, stream>>>(gridA, nullptr, 1.0f, gT);
    k_convm<<<dim3(32, 4, BB), 256, 0, stream>>>(gT, wB1, gridA);
    k_bnstat_a<<<dim3(64, BB), 256, 0, stream>>>(gridA, pst, R3);
    k_bnfin<<<1, 64, 0, stream>>>(pst, g1, be1, stats, BB, 1.0f / (BB * R3));
    k_t2bf<<<dim3(512, BB), 256, 0, stream>>>(gridA, stats, 0.1f, gT);
    k_convm<<<dim3(32, 4, BB), 256, 0, stream>>>(gT, wB2, gridA);
    k_bnstat_a<<<dim3(64, BB), 256, 0, stream>>>(gridA, pst, R3);
    k_bnfin<<<1, 64, 0, stream>>>(pst, g2, be2, stats + 128, BB, 1.0f / (BB * R3));
    k_bn_act<<<BB * CO * R3 / 4 / 256, 256, 0, stream>>>(gridA, stats + 128, gridA, 13, 0.1f);
    k_devox<<<dim3(NN / 64, BB), 256, 0, stream>>>(gridA, nc, vox);

    // fuzzy branch (pnum overlays gT region — gT dead after conv2)
    k_fuzzy<<<dim3(16, 8, BB), 256, 0, stream>>>(coords, featT, pnum, pden);
    k_combine<<<BB * 64 * NN / 256, 256, 0, stream>>>(pnum, pden, fzf);

    // point branch
    k_1x1<1><<<dim3(NN / 64, 4, BB), 256, 0, stream>>>(features, nullptr, nullptr, wp, bp, pt);
    k_bnstat_a<<<dim3(64, BB), 256, 0, stream>>>(pt, pst, NN);
    k_bnfin<<<1, 64, 0, stream>>>(pst, gp, bep, stats + 256, BB, 1.0f / (BB * NN));
    k_bn_act<<<BB * 64 * NN / 4 / 256, 256, 0, stream>>>(pt, stats + 256, pt, 10, 0.0f);

    // fuzzy proj
    k_1x1<1><<<dim3(NN / 64, 4, BB), 256, 0, stream>>>(fzf, nullptr, nullptr, wf, bf, fzc);

    // fusion
    k_1x1<3><<<dim3(NN / 64, 4, BB), 256, 0, stream>>>(vox, pt, fzc, wfu, bfu, fpre);
    k_bnstat_a<<<dim3(64, BB), 256, 0, stream>>>(fpre, pst, NN);
    k_bnfin<<<1, 64, 0, stream>>>(pst, gfu, befu, stats + 384, BB, 1.0f / (BB * NN));
    k_bn_act<<<BB * 64 * NN / 4 / 256, 256, 0, stream>>>(fpre, stats + 384, out, 10, 0.0f);

    hipMemcpyAsync(out + (size_t)BB * CO * NN, coords, (size_t)BB * 3 * NN * 4,
                   hipMemcpyDeviceToDevice, stream);
}

// Round 4
// 510.686 us; speedup vs baseline: 4.4657x; 1.1781x over previous
//
#include <hip/hip_runtime.h>
#include <hip/hip_bf16.h>
#include <math.h>

#define RR 32
#define R3 32768
#define BB 4
#define CI 64
#define CO 64
#define NN 4096

typedef short v8s __attribute__((ext_vector_type(8)));
typedef float v4f __attribute__((ext_vector_type(4)));
typedef unsigned short ushort_t;

__device__ __forceinline__ unsigned short f2bf(float f) {
    unsigned int u = __float_as_uint(f);
    unsigned int r = (u + 0x7FFFu + ((u >> 16) & 1u)) >> 16;
    return (unsigned short)r;
}

// ---------------- block reduce helpers ----------------
__device__ __forceinline__ float blockReduceSum(float v, float* sm) {
    int tid = threadIdx.x;
    sm[tid] = v; __syncthreads();
    for (int off = 128; off > 0; off >>= 1) {
        if (tid < off) sm[tid] += sm[tid + off];
        __syncthreads();
    }
    float r = sm[0]; __syncthreads();
    return r;
}
__device__ __forceinline__ float blockReduceMax(float v, float* sm) {
    int tid = threadIdx.x;
    sm[tid] = v; __syncthreads();
    for (int off = 128; off > 0; off >>= 1) {
        if (tid < off) sm[tid] = fmaxf(sm[tid], sm[tid + off]);
        __syncthreads();
    }
    float r = sm[0]; __syncthreads();
    return r;
}

// ---------------- voxel coords ----------------
__global__ void k_nc(const float* __restrict__ coords, float* __restrict__ nc,
                     int* __restrict__ vidx) {
    int b = blockIdx.x, tid = threadIdx.x;
    __shared__ float sm[256];
    const float* cb = coords + (size_t)b * 3 * NN;
    float s0 = 0, s1 = 0, s2 = 0;
    for (int n = tid; n < NN; n += 256) {
        s0 += cb[n]; s1 += cb[NN + n]; s2 += cb[2 * NN + n];
    }
    float m0 = blockReduceSum(s0, sm) * (1.0f / NN);
    float m1 = blockReduceSum(s1, sm) * (1.0f / NN);
    float m2 = blockReduceSum(s2, sm) * (1.0f / NN);
    float mx = 0;
    for (int n = tid; n < NN; n += 256) {
        float dx = cb[n] - m0, dy = cb[NN + n] - m1, dz = cb[2 * NN + n] - m2;
        mx = fmaxf(mx, dx * dx + dy * dy + dz * dz);
    }
    mx = blockReduceMax(mx, sm);
    float denom = 2.0f * sqrtf(mx);
    float mean[3] = {m0, m1, m2};
    for (int n = tid; n < NN; n += 256) {
        int vi[3];
        #pragma unroll
        for (int ax = 0; ax < 3; ax++) {
            float x = (cb[ax * NN + n] - mean[ax]) / denom + 0.5f;
            x = x * RR;
            x = fminf(fmaxf(x, 0.0f), (float)(RR - 1));
            nc[((size_t)b * 3 + ax) * NN + n] = x;
            vi[ax] = (int)rintf(x);
        }
        vidx[b * NN + n] = (vi[0] * RR + vi[1]) * RR + vi[2];
    }
}

// ---------------- scatter-mean ----------------
__global__ void k_scatter(const float* __restrict__ feat, const int* __restrict__ vidx,
                          float* __restrict__ grid, float* __restrict__ cnt) {
    int tid = threadIdx.x;
    int pid = blockIdx.x * 64 + (tid & 63);
    int cg = tid >> 6;
    int b = pid / NN, n = pid % NN;
    int idx = vidx[pid];
    if (cg == 0) atomicAdd(&cnt[b * R3 + idx], 1.0f);
    #pragma unroll 4
    for (int c = cg * 16; c < cg * 16 + 16; c++)
        atomicAdd(&grid[((size_t)(b * CI + c)) * R3 + idx], feat[((size_t)(b * CI + c)) * NN + n]);
}

__global__ void k_avg(float* __restrict__ grid, const float* __restrict__ cnt) {
    size_t i4 = (size_t)blockIdx.x * 256 + threadIdx.x;  // f4 index over B*CI*R3/4
    int v0 = (int)((i4 << 2) & (R3 - 1));
    int b = (int)(i4 >> 19);
    float4 g = ((float4*)grid)[i4];
    const float4 ct = *(const float4*)&cnt[b * R3 + v0];
    g.x /= fmaxf(ct.x, 1.0f); g.y /= fmaxf(ct.y, 1.0f);
    g.z /= fmaxf(ct.z, 1.0f); g.w /= fmaxf(ct.w, 1.0f);
    ((float4*)grid)[i4] = g;
}

// ---------------- features f32 -> bf16 (same [b][c][n] layout) ----------------
__global__ void k_f2b(const float* __restrict__ x, ushort_t* __restrict__ o) {
    size_t i = (size_t)blockIdx.x * 256 + threadIdx.x;  // over B*64*NN/8
    float4 a = ((const float4*)x)[i * 2];
    float4 b = ((const float4*)x)[i * 2 + 1];
    union { __hip_bfloat162 h[4]; uint4 u; } pk;
    pk.h[0] = __float22bfloat162_rn(make_float2(a.x, a.y));
    pk.h[1] = __float22bfloat162_rn(make_float2(a.z, a.w));
    pk.h[2] = __float22bfloat162_rn(make_float2(b.x, b.y));
    pk.h[3] = __float22bfloat162_rn(make_float2(b.z, b.w));
    ((uint4*)o)[i] = pk.u;
}

// ---------------- weight transform: wB[k][co][ci] bf16 ----------------
__global__ void k_twb(const float* __restrict__ w, ushort_t* __restrict__ wB) {
    int i = blockIdx.x * 256 + threadIdx.x;  // 27*64*64 = 110592
    int ci = i & 63, t = i >> 6;
    int co = t & 63, k = t >> 6;
    wB[i] = f2bf(w[((size_t)co * CI + ci) * 27 + k]);
}

// ---------------- fused (optional BN+lrelu) + transpose + bf16 cast ----------------
// in: x f32 [b][64][R3]; out: o bf16 [b][R3][64]
__global__ void k_t2bf(const float* __restrict__ x, const float* __restrict__ stats,
                       float slope, ushort_t* __restrict__ o) {
    __shared__ float ld[64][65];
    int b = blockIdx.y, s0 = blockIdx.x * 64, tid = threadIdx.x;
    int sl = tid & 63, cq = tid >> 6;
    const float* xb = x + (size_t)b * 64 * R3;
    #pragma unroll
    for (int k = 0; k < 16; k++) {
        int c = cq * 16 + k;
        ld[sl][c] = xb[(size_t)c * R3 + s0 + sl];
    }
    __syncthreads();
    int v = tid >> 2, q = tid & 3;
    unsigned int pk[8];
    #pragma unroll
    for (int j = 0; j < 8; j++) {
        int c = q * 16 + j * 2;
        float a = ld[v][c], d = ld[v][c + 1];
        if (stats) {
            a = a * stats[2 * c] + stats[2 * c + 1];
            d = d * stats[2 * c + 2] + stats[2 * c + 3];
            a = a > 0 ? a : slope * a;
            d = d > 0 ? d : slope * d;
        }
        pk[j] = (unsigned int)f2bf(a) | ((unsigned int)f2bf(d) << 16);
    }
    uint4* op = (uint4*)(o + ((size_t)(b * R3 + s0 + v)) * 64 + q * 16);
    op[0] = make_uint4(pk[0], pk[1], pk[2], pk[3]);
    op[1] = make_uint4(pk[4], pk[5], pk[6], pk[7]);
}

// ---------------- MFMA conv3d 3x3x3 ----------------
#define LOADKS(ks, AR, BR)                                                        \
  do {                                                                            \
    int _k = (ks) >> 1, _cih = (ks) & 1;                                          \
    int _dz = _k / 9, _rr = _k % 9, _dy = _rr / 3, _dx = _rr % 3;                 \
    unsigned _offin = (unsigned)((_dz * 1024 + _dy * 32 + _dx) * 64 + _cih * 32); \
    unsigned _offw = (unsigned)(_k * 4096 + _cih * 32);                           \
    _Pragma("unroll") for (int _f = 0; _f < 4; _f++)                              \
        BR[_f] = *(const v8s*)(sb[_f] + (lo[_f] + _offin));                       \
    _Pragma("unroll") for (int _m = 0; _m < 4; _m++)                              \
        AR[_m] = *(const v8s*)(wB + (loA[_m] + _offw));                           \
  } while (0)

#define MFMAKS(ks, AR, BR)                                                        \
  do {                                                                            \
    int _k = (ks) >> 1;                                                           \
    int _dz = _k / 9, _rr = _k % 9, _dy = _rr / 3, _dx = _rr % 3;                 \
    bool _zok = (unsigned)(z0 + _dz - 1) < 32u;                                   \
    v8s _bm[4];                                                                   \
    _Pragma("unroll") for (int _f = 0; _f < 4; _f++) {                            \
      bool _yok = (unsigned)(yw0 + (_f >> 1) + _dy - 1) < 32u;                    \
      bool _xok = (unsigned)((_f & 1) * 16 + l15 + _dx - 1) < 32u;                \
      _bm[_f] = (_zok && _yok && _xok) ? BR[_f] : vzero;                          \
    }                                                                             \
    _Pragma("unroll") for (int _m = 0; _m < 4; _m++)                              \
      _Pragma("unroll") for (int _f = 0; _f < 4; _f++)                            \
        acc[_m][_f] = __builtin_amdgcn_mfma_f32_16x16x32_bf16(AR[_m], _bm[_f],    \
                                                              acc[_m][_f], 0, 0, 0); \
  } while (0)

__global__ __launch_bounds__(256) void k_convm(const ushort_t* __restrict__ gT,
                                               const ushort_t* __restrict__ wB,
                                               float* __restrict__ out) {
    int z0 = blockIdx.x, yt = blockIdx.y, b = blockIdx.z;
    int tid = threadIdx.x;
    int w = __builtin_amdgcn_readfirstlane(tid >> 6);
    int lane = tid & 63;
    int l15 = lane & 15, l4 = lane >> 4;
    int yw0 = yt * 8 + w * 2;

    const ushort_t* gTb = gT + (size_t)b * R3 * 64;
    const ushort_t* sb[4];
    unsigned lo[4], loA[4];
    #pragma unroll
    for (int f = 0; f < 4; f++) {
        sb[f] = gTb + ((z0 - 1) * 1024 + (yw0 + (f >> 1) - 1) * 32 - 1) * 64;
        lo[f] = (unsigned)((((f & 1) * 16 + l15) * 64) + l4 * 8);
    }
    #pragma unroll
    for (int m = 0; m < 4; m++)
        loA[m] = (unsigned)(((m * 16 + l15) * 64) + l4 * 8);

    const v8s vzero = {};
    v4f acc[4][4];
    #pragma unroll
    for (int m = 0; m < 4; m++)
        #pragma unroll
        for (int f = 0; f < 4; f++)
            acc[m][f] = (v4f){0.0f, 0.0f, 0.0f, 0.0f};

    v8s A0[4], B0[4], A1[4], B1[4];
    LOADKS(0, A0, B0);
    for (int t = 0; t < 54; t += 2) {
        LOADKS(t + 1, A1, B1);
        MFMAKS(t, A0, B0);
        if (t < 52) LOADKS(t + 2, A0, B0);
        MFMAKS(t + 1, A1, B1);
    }

    #pragma unroll
    for (int m = 0; m < 4; m++) {
        #pragma unroll
        for (int f = 0; f < 4; f++) {
            int y = yw0 + (f >> 1);
            int x = (f & 1) * 16 + l15;
            #pragma unroll
            for (int r = 0; r < 4; r++) {
                int co = m * 16 + l4 * 4 + r;
                out[((size_t)(b * CO + co)) * R3 + z0 * 1024 + y * 32 + x] = acc[m][f][r];
            }
        }
    }
}

// ---------------- BN stats (2-stage) ----------------
__global__ void k_bnstat_a(const float* __restrict__ x, float* __restrict__ pst, int len) {
    int c = blockIdx.x, b = blockIdx.y, tid = threadIdx.x;
    const float4* xp = (const float4*)(x + ((size_t)(b * 64 + c)) * len);
    int n4 = len >> 2;
    float s = 0, q = 0;
    for (int i = tid; i < n4; i += 256) {
        float4 v = xp[i];
        s += v.x + v.y + v.z + v.w;
        q += v.x * v.x + v.y * v.y + v.z * v.z + v.w * v.w;
    }
    __shared__ float rs[256], rq[256];
    rs[tid] = s; rq[tid] = q; __syncthreads();
    for (int off = 128; off > 0; off >>= 1) {
        if (tid < off) { rs[tid] += rs[tid + off]; rq[tid] += rq[tid + off]; }
        __syncthreads();
    }
    if (tid == 0) {
        pst[(c * gridDim.y + b) * 2] = rs[0];
        pst[(c * gridDim.y + b) * 2 + 1] = rq[0];
    }
}

__global__ void k_bnfin(const float* __restrict__ pst, const float* __restrict__ g,
                        const float* __restrict__ be, float* __restrict__ stats,
                        int nb, float invcnt) {
    int c = threadIdx.x;
    float s = 0, q = 0;
    for (int b = 0; b < nb; b++) {
        s += pst[(c * nb + b) * 2];
        q += pst[(c * nb + b) * 2 + 1];
    }
    float mean = s * invcnt;
    float var = q * invcnt - mean * mean;
    float sc = g[c] * rsqrtf(var + 1e-4f);
    stats[2 * c] = sc;
    stats[2 * c + 1] = be[c] - mean * sc;
}

__global__ void k_bn_act(const float* __restrict__ x, const float* __restrict__ stats,
                         float* __restrict__ out, int shift, float slope) {
    size_t i = (size_t)blockIdx.x * 256 + threadIdx.x;
    int c = (int)((i >> shift) & 63);
    float sc = stats[2 * c], sh = stats[2 * c + 1];
    float4 v = ((const float4*)x)[i];
    v.x = v.x * sc + sh; v.y = v.y * sc + sh; v.z = v.z * sc + sh; v.w = v.w * sc + sh;
    v.x = v.x > 0 ? v.x : slope * v.x;
    v.y = v.y > 0 ? v.y : slope * v.y;
    v.z = v.z > 0 ? v.z : slope * v.z;
    v.w = v.w > 0 ? v.w : slope * v.w;
    ((float4*)out)[i] = v;
}

// ---------------- devoxelize ----------------
__global__ void k_devox(const float* __restrict__ v2, const float* __restrict__ nc,
                        float* __restrict__ out) {
    int b = blockIdx.y;
    int n = blockIdx.x * 64 + (threadIdx.x & 63);
    int cg = threadIdx.x >> 6;
    float x = nc[((size_t)b * 3 + 0) * NN + n];
    float y = nc[((size_t)b * 3 + 1) * NN + n];
    float z = nc[((size_t)b * 3 + 2) * NN + n];
    float fx = floorf(x), fy = floorf(y), fz = floorf(z);
    int lx = (int)fx, ly = (int)fy, lz = (int)fz;
    int hx = min(lx + 1, RR - 1), hy = min(ly + 1, RR - 1), hz = min(lz + 1, RR - 1);
    float frx = x - fx, fry = y - fy, frz = z - fz;
    int xx[2] = {lx, hx}, yy[2] = {ly, hy}, zz[2] = {lz, hz};
    float wx[2] = {1.0f - frx, frx}, wy[2] = {1.0f - fry, fry}, wz[2] = {1.0f - frz, frz};
    int idx[8]; float wt[8];
    #pragma unroll
    for (int dx = 0; dx < 2; dx++)
        #pragma unroll
        for (int dy = 0; dy < 2; dy++)
            #pragma unroll
            for (int dz = 0; dz < 2; dz++) {
                idx[dx * 4 + dy * 2 + dz] = (xx[dx] * RR + yy[dy]) * RR + zz[dz];
                wt[dx * 4 + dy * 2 + dz] = wx[dx] * wy[dy] * wz[dz];
            }
    for (int c = cg * 16; c < cg * 16 + 16; c++) {
        const float* g = v2 + ((size_t)(b * CO + c)) * R3;
        float s = 0;
        #pragma unroll
        for (int k = 0; k < 8; k++) s += g[idx[k]] * wt[k];
        out[((size_t)(b * CO + c)) * NN + n] = s;
    }
}

// ---------------- fuzzy attention v3: MFMA ----------------
// out[c][n] = sum_m F[c][m] * P[m][n], P = exp(10*cn.cm)
// A = featb bf16 [b][c][m] (native layout), B = P built in-register.
// grid (64 n-tiles of 64, 2 m-chunks, B), 256 thr (4 waves x 16 n).
__global__ __launch_bounds__(256) void k_fuzzym(const float* __restrict__ coords,
                                                const ushort_t* __restrict__ featb,
                                                float* __restrict__ pnum,
                                                float* __restrict__ pden) {
    __shared__ float cm[3][2048];
    int b = blockIdx.z, mc = blockIdx.y, nt = blockIdx.x;
    int tid = threadIdx.x;
    int w = tid >> 6, lane = tid & 63, l15 = lane & 15, l4 = lane >> 4;
    int m0 = mc * 2048;

    for (int i = tid; i < 2048; i += 256) {
        float a0 = coords[((size_t)b * 3 + 0) * NN + m0 + i];
        float a1 = coords[((size_t)b * 3 + 1) * NN + m0 + i];
        float a2 = coords[((size_t)b * 3 + 2) * NN + m0 + i];
        float inv = 1.0f / fmaxf(sqrtf(a0 * a0 + a1 * a1 + a2 * a2), 1e-12f);
        cm[0][i] = a0 * inv; cm[1][i] = a1 * inv; cm[2][i] = a2 * inv;
    }

    int n = nt * 64 + w * 16 + l15;
    float q0 = coords[((size_t)b * 3 + 0) * NN + n];
    float q1 = coords[((size_t)b * 3 + 1) * NN + n];
    float q2 = coords[((size_t)b * 3 + 2) * NN + n];
    float qi = 10.0f / fmaxf(sqrtf(q0 * q0 + q1 * q1 + q2 * q2), 1e-12f);
    q0 *= qi; q1 *= qi; q2 *= qi;

    const ushort_t* fb = featb + (size_t)b * 64 * NN + m0;
    v4f acc[4];
    #pragma unroll
    for (int cb = 0; cb < 4; cb++) acc[cb] = (v4f){0.0f, 0.0f, 0.0f, 0.0f};
    float den = 0.0f;

    __syncthreads();
    for (int t = 0; t < 64; t++) {
        int mo = t * 32 + l4 * 8;
        float e[8];
        #pragma unroll
        for (int jj = 0; jj < 2; jj++) {
            float4 x0 = *(const float4*)&cm[0][mo + jj * 4];
            float4 x1 = *(const float4*)&cm[1][mo + jj * 4];
            float4 x2 = *(const float4*)&cm[2][mo + jj * 4];
            e[jj * 4 + 0] = __expf(q0 * x0.x + q1 * x1.x + q2 * x2.x);
            e[jj * 4 + 1] = __expf(q0 * x0.y + q1 * x1.y + q2 * x2.y);
            e[jj * 4 + 2] = __expf(q0 * x0.z + q1 * x1.z + q2 * x2.z);
            e[jj * 4 + 3] = __expf(q0 * x0.w + q1 * x1.w + q2 * x2.w);
        }
        den += ((e[0] + e[1]) + (e[2] + e[3])) + ((e[4] + e[5]) + (e[6] + e[7]));
        union { __hip_bfloat162 h[4]; v8s v; } pk;
        pk.h[0] = __float22bfloat162_rn(make_float2(e[0], e[1]));
        pk.h[1] = __float22bfloat162_rn(make_float2(e[2], e[3]));
        pk.h[2] = __float22bfloat162_rn(make_float2(e[4], e[5]));
        pk.h[3] = __float22bfloat162_rn(make_float2(e[6], e[7]));
        #pragma unroll
        for (int cb = 0; cb < 4; cb++) {
            v8s A = *(const v8s*)(fb + (size_t)(cb * 16 + l15) * NN + mo);
            acc[cb] = __builtin_amdgcn_mfma_f32_16x16x32_bf16(A, pk.v, acc[cb], 0, 0, 0);
        }
    }

    den += __shfl_xor(den, 16);
    den += __shfl_xor(den, 32);

    size_t obase = ((size_t)(b * 2 + mc)) * 64 * NN;
    #pragma unroll
    for (int cb = 0; cb < 4; cb++)
        #pragma unroll
        for (int r = 0; r < 4; r++)
            pnum[obase + (size_t)(cb * 16 + l4 * 4 + r) * NN + n] = acc[cb][r];
    if (l4 == 0) pden[((size_t)(b * 2 + mc)) * NN + n] = den;
}

__global__ void k_combine2(const float* __restrict__ pnum, const float* __restrict__ pden,
                           float* __restrict__ fzf) {
    int i = blockIdx.x * 256 + threadIdx.x;  // B*64*NN
    int b = i >> 18, c = (i >> 12) & 63, n = i & 4095;
    float num = pnum[((size_t)(b * 2 + 0) * 64 + c) * NN + n] +
                pnum[((size_t)(b * 2 + 1) * 64 + c) * NN + n];
    float den = pden[((size_t)(b * 2 + 0)) * NN + n] +
                pden[((size_t)(b * 2 + 1)) * NN + n];
    fzf[((size_t)(b * 64 + c)) * NN + n] = num / den;
}

// ---------------- 1x1 conv ----------------
template <int NSEG>
__global__ __launch_bounds__(256) void k_1x1(const float* __restrict__ inA,
                                             const float* __restrict__ inB,
                                             const float* __restrict__ inC,
                                             const float* __restrict__ w,
                                             const float* __restrict__ bias,
                                             float* __restrict__ out) {
    __shared__ float lw[NSEG * 64 * 16];
    int b = blockIdx.z, ob = blockIdx.y;
    int n = blockIdx.x * 64 + (threadIdx.x & 63);
    int og = threadIdx.x >> 6;
    const int CI3 = NSEG * 64;
    for (int i = threadIdx.x; i < CI3 * 16; i += 256) {
        int c = i >> 4, o = i & 15;
        lw[c * 16 + o] = w[(size_t)(ob * 16 + o) * CI3 + c];
    }
    __syncthreads();
    float acc[4] = {0, 0, 0, 0};
    const float* segs[3] = {inA, inB, inC};
    #pragma unroll
    for (int sg = 0; sg < NSEG; sg++) {
        const float* src = segs[sg] + (size_t)b * 64 * NN + n;
        #pragma unroll 8
        for (int c = 0; c < 64; c++) {
            float x = src[(size_t)c * NN];
            float4 wv = *(const float4*)&lw[(sg * 64 + c) * 16 + og * 4];
            acc[0] += x * wv.x; acc[1] += x * wv.y;
            acc[2] += x * wv.z; acc[3] += x * wv.w;
        }
    }
    #pragma unroll
    for (int j = 0; j < 4; j++)
        out[((size_t)(b * 64 + ob * 16 + og * 4 + j)) * NN + n] = acc[j] + bias[ob * 16 + og * 4 + j];
}

// ---------------- launcher ----------------
extern "C" void kernel_launch(void* const* d_in, const int* in_sizes, int n_in,
                              void* d_out, int out_size, void* d_ws, size_t ws_size,
                              hipStream_t stream) {
    const float* features = (const float*)d_in[0];
    const float* coords = (const float*)d_in[1];
    const float* w1 = (const float*)d_in[2];
    // b1 (d_in[3]) skipped: cancelled exactly by BN1 mean subtraction
    const float* g1 = (const float*)d_in[4];
    const float* be1 = (const float*)d_in[5];
    const float* w2 = (const float*)d_in[6];
    // b2 (d_in[7]) skipped: cancelled by BN2
    const float* g2 = (const float*)d_in[8];
    const float* be2 = (const float*)d_in[9];
    const float* wp = (const float*)d_in[10];
    const float* bp = (const float*)d_in[11];
    const float* gp = (const float*)d_in[12];
    const float* bep = (const float*)d_in[13];
    const float* wf = (const float*)d_in[14];
    const float* bf = (const float*)d_in[15];
    const float* wfu = (const float*)d_in[16];
    const float* bfu = (const float*)d_in[17];
    const float* gfu = (const float*)d_in[18];
    const float* befu = (const float*)d_in[19];

    float* ws = (float*)d_ws;
    float* nc = ws;                        // 49152
    int* vidx = (int*)(ws + 49152);        // 16384 (pst overlays after scatter)
    float* pst = ws + 49152;
    float* cnt = ws + 65536;               // 131072 (pden overlays after k_avg)
    float* pden = cnt;
    float* gridA = ws + 196608;            // 8388608 f32 work grid
    float* gTpool = ws + 8585216;          // 8388608 floats: gT bf16 / pnum later
    ushort_t* gT = (ushort_t*)gTpool;
    float* pnum = gTpool;                  // 2*64*NN floats needed (fits easily)
    float* stats = ws + 16973824;          // 512
    float* voxreg = ws + 16974336;         // 1048576 (wB1/wB2 live here until devox)
    ushort_t* wB1 = (ushort_t*)voxreg;     // 110592 ushorts
    ushort_t* wB2 = wB1 + 110592;
    float* vox = voxreg;
    float* pt = ws + 18022912;
    float* fzf = ws + 19071488;
    float* fzc = ws + 20120064;
    float* fpre = ws + 21168640;           // featb overlays (consumed before fusion)
    ushort_t* featb = (ushort_t*)fpre;     // 524288 ushorts

    float* out = (float*)d_out;

    hipMemsetAsync(cnt, 0, (size_t)(131072 + 8388608) * 4, stream);

    // prep
    k_f2b<<<BB * 64 * NN / 8 / 256, 256, 0, stream>>>(features, featb);
    k_twb<<<432, 256, 0, stream>>>(w1, wB1);
    k_twb<<<432, 256, 0, stream>>>(w2, wB2);
    k_nc<<<BB, 256, 0, stream>>>(coords, nc, vidx);
    k_scatter<<<BB * NN / 64, 256, 0, stream>>>(features, vidx, gridA, cnt);
    k_avg<<<BB * CI * R3 / 4 / 256, 256, 0, stream>>>(gridA, cnt);

    // voxel branch (MFMA convs)
    k_t2bf<<<dim3(512, BB), 256, 0, stream>>>(gridA, nullptr, 1.0f, gT);
    k_convm<<<dim3(32, 4, BB), 256, 0, stream>>>(gT, wB1, gridA);
    k_bnstat_a<<<dim3(64, BB), 256, 0, stream>>>(gridA, pst, R3);
    k_bnfin<<<1, 64, 0, stream>>>(pst, g1, be1, stats, BB, 1.0f / (BB * R3));
    k_t2bf<<<dim3(512, BB), 256, 0, stream>>>(gridA, stats, 0.1f, gT);
    k_convm<<<dim3(32, 4, BB), 256, 0, stream>>>(gT, wB2, gridA);
    k_bnstat_a<<<dim3(64, BB), 256, 0, stream>>>(gridA, pst, R3);
    k_bnfin<<<1, 64, 0, stream>>>(pst, g2, be2, stats + 128, BB, 1.0f / (BB * R3));
    k_bn_act<<<BB * CO * R3 / 4 / 256, 256, 0, stream>>>(gridA, stats + 128, gridA, 13, 0.1f);
    k_devox<<<dim3(NN / 64, BB), 256, 0, stream>>>(gridA, nc, vox);

    // fuzzy branch (pnum overlays gT region — gT dead after conv2)
    k_fuzzym<<<dim3(64, 2, BB), 256, 0, stream>>>(coords, featb, pnum, pden);
    k_combine2<<<BB * 64 * NN / 256, 256, 0, stream>>>(pnum, pden, fzf);

    // point branch
    k_1x1<1><<<dim3(NN / 64, 4, BB), 256, 0, stream>>>(features, nullptr, nullptr, wp, bp, pt);
    k_bnstat_a<<<dim3(64, BB), 256, 0, stream>>>(pt, pst, NN);
    k_bnfin<<<1, 64, 0, stream>>>(pst, gp, bep, stats + 256, BB, 1.0f / (BB * NN));
    k_bn_act<<<BB * 64 * NN / 4 / 256, 256, 0, stream>>>(pt, stats + 256, pt, 10, 0.0f);

    // fuzzy proj
    k_1x1<1><<<dim3(NN / 64, 4, BB), 256, 0, stream>>>(fzf, nullptr, nullptr, wf, bf, fzc);

    // fusion
    k_1x1<3><<<dim3(NN / 64, 4, BB), 256, 0, stream>>>(vox, pt, fzc, wfu, bfu, fpre);
    k_bnstat_a<<<dim3(64, BB), 256, 0, stream>>>(fpre, pst, NN);
    k_bnfin<<<1, 64, 0, stream>>>(pst, gfu, befu, stats + 384, BB, 1.0f / (BB * NN));
    k_bn_act<<<BB * 64 * NN / 4 / 256, 256, 0, stream>>>(fpre, stats + 384, out, 10, 0.0f);

    hipMemcpyAsync(out + (size_t)BB * CO * NN, coords, (size_t)BB * 3 * NN * 4,
                   hipMemcpyDeviceToDevice, stream);
}